// Round 15
// baseline (2061.811 us; speedup 1.0000x reference)
//
#include <hip/hip_runtime.h>
#include <array>

#define DEV __device__ __forceinline__

typedef float v2f __attribute__((ext_vector_type(2)));

// ---------------------------------------------------------------------------
// Compile-time real Clebsch-Gordan tables (mirror of reference _build_paths)
// ---------------------------------------------------------------------------
namespace cgt {

constexpr double FACT[14] = {1.,1.,2.,6.,24.,120.,720.,5040.,40320.,362880.,
                             3628800.,39916800.,479001600.,6227020800.};

constexpr double csqrt(double x){
  if(x <= 0.0) return 0.0;
  double g = x > 1.0 ? x : 1.0;
  for(int i=0;i<28;++i) g = 0.5*(g + x/g);
  return g;
}

constexpr double cgc(int l1,int m1,int l2,int m2,int l3,int m3){
  if(m3 != m1+m2) return 0.0;
  double pre = (2.0*l3+1.0)*FACT[l1+l2-l3]*FACT[l1-l2+l3]*FACT[-l1+l2+l3]/FACT[l1+l2+l3+1];
  pre = csqrt(pre * FACT[l1+m1]*FACT[l1-m1]*FACT[l2+m2]*FACT[l2-m2]*FACT[l3+m3]*FACT[l3-m3]);
  double s = 0.0;
  for(int k=0;k<=l1+l2-l3;++k){
    int d1=l1+l2-l3-k, d2=l1-m1-k, d3=l2+m2-k, d4=l3-l2+m1+k, d5=l3-l1-m2+k;
    if(d1<0||d2<0||d3<0||d4<0||d5<0) continue;
    double den = FACT[k]*FACT[d1]*FACT[d2]*FACT[d3]*FACT[d4]*FACT[d5];
    s += ((k&1)? -1.0 : 1.0)/den;
  }
  return pre*s;
}

struct C2 { double re, im; };

// U_l[a, m+l] of the complex->real SH change of basis
constexpr C2 uent(int l, int a, int m){
  const double s = 0.70710678118654752440;
  int mr = a - l;
  if(mr == 0) return (m==0) ? C2{1.0,0.0} : C2{0.0,0.0};
  if(mr > 0){
    if(m ==  mr) return C2{ (mr&1)? -s : s, 0.0};
    if(m == -mr) return C2{ s, 0.0};
    return C2{0.0,0.0};
  }
  if(m ==  mr) return C2{0.0, s};
  if(m == -mr) return C2{0.0, ((-mr)&1)? s : -s};
  return C2{0.0,0.0};
}

constexpr float crent(int l1,int l2,int l3,int a,int b,int c){
  double re = 0.0;
  int mrc = c - l3;
  for(int i=0;i<2;++i){
    if(i==1 && a==l1) break;
    int m1 = (i==0) ? (a-l1) : (l1-a);
    for(int j=0;j<2;++j){
      if(j==1 && b==l2) break;
      int m2 = (j==0) ? (b-l2) : (l2-b);
      int m3 = m1+m2;
      if(m3 < -l3 || m3 > l3) continue;
      if(m3 != mrc && m3 != -mrc) continue;   // U3 row-c sparsity
      C2 u1 = uent(l1,a,m1), u2 = uent(l2,b,m2), u3 = uent(l3,c,m3);
      double u3re = u3.re, u3im = -u3.im;     // conj
      double pr = u1.re*u2.re - u1.im*u2.im;
      double pi = u1.re*u2.im + u1.im*u2.re;
      double rr = pr*u3re - pi*u3im;          // Re(u1*u2*conj(u3))
      if(rr == 0.0) continue;
      re += rr * cgc(l1,m1,l2,m2,l3,m3);
    }
  }
  return (float)re;
}

template<int L1,int L2,int L3>
constexpr std::array<float,(2*L1+1)*(2*L2+1)*(2*L3+1)> build_path(){
  std::array<float,(2*L1+1)*(2*L2+1)*(2*L3+1)> r{};
  for(int a=0;a<2*L1+1;++a)
    for(int b=0;b<2*L2+1;++b)
      for(int c=0;c<2*L3+1;++c)
        r[(a*(2*L2+1)+b)*(2*L3+1)+c] = crent(L1,L2,L3,a,b,c);
  return r;
}

} // namespace cgt

// ---------------------------------------------------------------------------
// R15: attack the exposed LDS latency with TLP, not ILP.  R13 showed the
// compiler pins VGPR=64 and refuses pragma-driven pipelining (unroll 2 was
// neutral).  Occupancy was ~3.5 waves/SIMD, limited by the 26.6KB/block
// LDS staging buffer.  deg_dense is BLOCK-DIAGONAL per degree: each dense
// pass reads only its degree's <=9 rows.  Stage per degree into a ping-pong
// pair of [9][64] buffers (ping-pong avoids WAR stalls between degree D's
// broadcast reads and degree D+1's writes).  LDS/block 26.6KB -> 19.4KB ->
// 8 blocks/CU; with VGPR=64 the HW allows 8 waves/SIMD (2.3x TLP) to hide
// the ~35cyc/read exposure.
// ---------------------------------------------------------------------------
__device__ constexpr int DEGA[25] = {0,1,1,1,2,2,2,2,2,3,3,3,3,3,3,3,4,4,4,4,4,4,4,4,4};

DEV v2f fma2(v2f a, v2f b, v2f c){
#if __has_builtin(__builtin_elementwise_fma)
  return __builtin_elementwise_fma(a,b,c);
#else
  return (v2f){fmaf(a.x,b.x,c.x), fmaf(a.y,b.y,c.y)};
#endif
}

DEV float rdl(float v, int l){   // fallback kernel only
  return __int_as_float(__builtin_amdgcn_readlane(__float_as_int(v), l));
}

// One CG path; u,v accessed with compile-time strides (US/VS).
template<int L1,int L2,int L3,int P,int US,int VS>
DEV void cg_path(const float* __restrict__ wp, int lane,
                 const float* __restrict__ u, const float* __restrict__ v,
                 float* __restrict__ t){
  constexpr auto C = cgt::build_path<L1,L2,L3>();
  const float wpv = wp[P*64 + lane];
  #pragma unroll
  for(int a=0;a<2*L1+1;++a){
    #pragma unroll
    for(int b=0;b<2*L2+1;++b){
      float uvw = 0.0f; bool made = false;
      #pragma unroll
      for(int c=0;c<2*L3+1;++c){
        const float cv = C[(a*(2*L2+1)+b)*(2*L3+1)+c];
        if(cv != 0.0f){
          if(!made){ uvw = u[(L1*L1+a)*US]*v[(L2*L2+b)*VS]*wpv; made = true; }
          t[L3*L3+c] = fmaf(cv, uvw, t[L3*L3+c]);
        }
      }
    }
  }
}

template<int US,int VS>
DEV void cg_all(const float* __restrict__ wp, int lane,
                const float* __restrict__ u, const float* __restrict__ v,
                float* __restrict__ t){
  cg_path<0,0,0,0,US,VS>(wp,lane,u,v,t);  cg_path<0,1,1,1,US,VS>(wp,lane,u,v,t);
  cg_path<0,2,2,2,US,VS>(wp,lane,u,v,t);  cg_path<0,3,3,3,US,VS>(wp,lane,u,v,t);
  cg_path<0,4,4,4,US,VS>(wp,lane,u,v,t);
  cg_path<1,0,1,5,US,VS>(wp,lane,u,v,t);  cg_path<1,1,0,6,US,VS>(wp,lane,u,v,t);
  cg_path<1,1,2,7,US,VS>(wp,lane,u,v,t);  cg_path<1,2,1,8,US,VS>(wp,lane,u,v,t);
  cg_path<1,2,3,9,US,VS>(wp,lane,u,v,t);  cg_path<1,3,2,10,US,VS>(wp,lane,u,v,t);
  cg_path<1,3,4,11,US,VS>(wp,lane,u,v,t); cg_path<1,4,3,12,US,VS>(wp,lane,u,v,t);
  cg_path<2,0,2,13,US,VS>(wp,lane,u,v,t); cg_path<2,1,1,14,US,VS>(wp,lane,u,v,t);
  cg_path<2,1,3,15,US,VS>(wp,lane,u,v,t); cg_path<2,2,0,16,US,VS>(wp,lane,u,v,t);
  cg_path<2,2,2,17,US,VS>(wp,lane,u,v,t); cg_path<2,2,4,18,US,VS>(wp,lane,u,v,t);
  cg_path<2,3,1,19,US,VS>(wp,lane,u,v,t); cg_path<2,3,3,20,US,VS>(wp,lane,u,v,t);
  cg_path<2,4,2,21,US,VS>(wp,lane,u,v,t); cg_path<2,4,4,22,US,VS>(wp,lane,u,v,t);
  cg_path<3,0,3,23,US,VS>(wp,lane,u,v,t); cg_path<3,1,2,24,US,VS>(wp,lane,u,v,t);
  cg_path<3,1,4,25,US,VS>(wp,lane,u,v,t); cg_path<3,2,1,26,US,VS>(wp,lane,u,v,t);
  cg_path<3,2,3,27,US,VS>(wp,lane,u,v,t); cg_path<3,3,0,28,US,VS>(wp,lane,u,v,t);
  cg_path<3,3,2,29,US,VS>(wp,lane,u,v,t); cg_path<3,3,4,30,US,VS>(wp,lane,u,v,t);
  cg_path<3,4,1,31,US,VS>(wp,lane,u,v,t); cg_path<3,4,3,32,US,VS>(wp,lane,u,v,t);
  cg_path<4,0,4,33,US,VS>(wp,lane,u,v,t); cg_path<4,1,3,34,US,VS>(wp,lane,u,v,t);
  cg_path<4,2,2,35,US,VS>(wp,lane,u,v,t); cg_path<4,2,4,36,US,VS>(wp,lane,u,v,t);
  cg_path<4,3,1,37,US,VS>(wp,lane,u,v,t); cg_path<4,3,3,38,US,VS>(wp,lane,u,v,t);
  cg_path<4,4,0,39,US,VS>(wp,lane,u,v,t); cg_path<4,4,2,40,US,VS>(wp,lane,u,v,t);
  cg_path<4,4,4,41,US,VS>(wp,lane,u,v,t);
}

// Stage the 2D+1 rows of degree D (lane-owned t columns) into Bq.
template<int D>
DEV void stage_rows(float* __restrict__ Bq, int lane, const float* __restrict__ t){
  #pragma unroll
  for(int m=0;m<2*D+1;++m) Bq[m*64+lane] = t[D*D+m];
}

// Degree-D packed dense: uv[D*D+m] += sum_f Bq[m][f]*(WA,WB)[D][f][g].
// Bq holds ONLY degree D's rows (local row index m).
template<int D>
DEV void dense_uv2_deg(const float* __restrict__ Wint, int lane,
                       const float* __restrict__ Bq, v2f* __restrict__ uv){
  constexpr int L0 = D*D, N = 2*D+1;
  const float* wb = Wint + lane*2;
  #pragma unroll 2
  for(int f0=0; f0<64; f0+=4){
    const float* p = wb + (D*4096 + f0*64)*2;
    const v2f w0 = *(const v2f*)(p);
    const v2f w1 = *(const v2f*)(p+128);
    const v2f w2 = *(const v2f*)(p+256);
    const v2f w3 = *(const v2f*)(p+384);
    #pragma unroll
    for(int m=0;m<N;++m){
      const float4 tv = *(const float4*)(Bq + m*64 + f0);
      v2f acc = uv[L0+m];
      acc = fma2(w0,(v2f){tv.x,tv.x},acc);
      acc = fma2(w1,(v2f){tv.y,tv.y},acc);
      acc = fma2(w2,(v2f){tv.z,tv.z},acc);
      acc = fma2(w3,(v2f){tv.w,tv.w},acc);
      uv[L0+m] = acc;
    }
  }
}

// Degree-D scalar out dense: yn[D*D+m] += sum_f Bq[m][f]*W[D][f][g].
template<int D>
DEV void dense_out1_deg(const float* __restrict__ W, int lane,
                        const float* __restrict__ Bq, float* __restrict__ yn){
  constexpr int L0 = D*D, N = 2*D+1;
  const float* wb = W + lane;
  #pragma unroll 2
  for(int f0=0; f0<64; f0+=4){
    const float* p = wb + D*4096 + f0*64;
    const float w0 = p[0], w1 = p[64], w2 = p[128], w3 = p[192];
    #pragma unroll
    for(int m=0;m<N;++m){
      const float4 tv = *(const float4*)(Bq + m*64 + f0);
      float acc = yn[L0+m];
      acc = fmaf(tv.x,w0,acc);
      acc = fmaf(tv.y,w1,acc);
      acc = fmaf(tv.z,w2,acc);
      acc = fmaf(tv.w,w3,acc);
      yn[L0+m] = acc;
    }
  }
}

// ---------------------------------------------------------------------------
// Kernels
// ---------------------------------------------------------------------------
// Precompute: W12 = interleave(W1a,W2a); WAB = interleave(Woa@W1b, Woa@W2b);
// WO = Wob * twt.  One thread per (d,f,g).
__global__ void wfuse_kernel(const float* __restrict__ W1a, const float* __restrict__ W2a,
                             const float* __restrict__ Woa, const float* __restrict__ W1b,
                             const float* __restrict__ W2b, const float* __restrict__ Wob,
                             const float* __restrict__ twt,
                             float* __restrict__ W12, float* __restrict__ WAB,
                             float* __restrict__ WO){
  const int i = blockIdx.x*256 + threadIdx.x;   // 0 .. 20479
  if(i >= 20480) return;
  const int d = i >> 12, rem = i & 4095, f = rem >> 6, g = rem & 63;
  W12[2*i+0] = W1a[i];
  W12[2*i+1] = W2a[i];
  const float* wo  = Woa + d*4096 + f*64;   // row f: [h]
  const float* wb1 = W1b + d*4096 + g;      // col g: [h][g] stride 64
  const float* wb2 = W2b + d*4096 + g;
  float sa = 0.0f, sb = 0.0f;
  for(int h=0; h<64; ++h){
    const float a = wo[h];
    sa = fmaf(a, wb1[h*64], sa);
    sb = fmaf(a, wb2[h*64], sb);
  }
  WAB[2*i+0] = sa;
  WAB[2*i+1] = sb;
  WO[i] = Wob[i] * twt[d*64 + g];
}

// A[s][g] = emb_table[s] @ W_emb_t  (species-deduped edge scale table)
__global__ void atab_kernel(const float* __restrict__ emb, const float* __restrict__ Wemb,
                            float* __restrict__ A){
  const int s = blockIdx.x;
  const int g = threadIdx.x;
  float acc = 0.0f;
  for(int f=0; f<64; ++f) acc = fmaf(emb[s*64+f], Wemb[f*64+g], acc);
  A[s*64+g] = acc;
}

// out[a,0,:] += A[Z[a]]
__global__ void self_kernel(const int* __restrict__ an, const float* __restrict__ A,
                            float* __restrict__ out, int NA){
  const int i = blockIdx.x*256 + threadIdx.x;
  if(i < NA*64){
    const int a = i>>6, g = i&63;
    out[(size_t)a*1600 + g] += A[an[a]*64 + g];
  }
}

// Fused edge kernel: one wave per edge (lane = feature g).
// Per-wave LDS: ping-pong pair of [9][64] degree buffers + [64] rad
// = 1216 floats = 4864B; x4 waves = 19456B/block -> 8 blocks/CU.
__global__ __launch_bounds__(256)
void edge_kernel(
    const int* __restrict__ an, const int* __restrict__ nbr, const float* __restrict__ disp,
    const float* __restrict__ Wrad,
    const float* __restrict__ W12, const float* __restrict__ WAB,
    const float* __restrict__ wpa, const float* __restrict__ wpb,
    const float* __restrict__ WO, const float* __restrict__ Atab,
    float* __restrict__ out, int NE)
{
  __shared__ __align__(16) float lds[4*1216];
  const int lane = threadIdx.x & 63;
  const int w    = threadIdx.x >> 6;
  const int e0   = blockIdx.x*4 + w;
  const bool active = e0 < NE;
  const int e = active ? e0 : 0;
  float* B0   = lds + w*1216;    // [9][64] degree buffer (ping)
  float* B1   = B0 + 576;        // [9][64] degree buffer (pong)
  float* Brad = B0 + 1152;       // [64] rad staging

  // ---- radial scalar chain (wave-uniform r) + per-lane rad[f=lane] ----
  const int ai = nbr[2*e];
  const int aj = nbr[2*e+1];
  const float dx = disp[3*e], dy = disp[3*e+1], dz = disp[3*e+2];
  const float r  = sqrtf(fmaf(dx,dx,fmaf(dy,dy,dz*dz)) + 1e-12f);
  const float ir = 1.0f/r;
  const float x = dx*ir, y = dy*ir, z = dz*ir;
  const float fc = (r < 5.0f) ? (0.5f*(cosf(0.62831853071795864769f*r)+1.0f)) : 0.0f;

  const int Zj = an[aj];
  const float* Wr = Wrad + Zj*1024 + lane;
  float rad = 0.0f;
  #pragma unroll
  for(int k=0;k<16;++k){
    const float d  = r - (float)k*(1.0f/3.0f);
    const float rb = __expf(-10.24f*d*d)*fc;
    rad = fmaf(rb, Wr[k*64], rad);
  }
  Brad[lane] = rad;   // same-wave LDS ops are in-order: no barrier needed

  // ---- layer-0 rank-1 collapse with packed (W1a,W2a):
  //      rw[d] = sum_f rad[f] * (W1a,W2a)[d][f][g], rad[f] via LDS broadcast
  v2f rw[5];
  #pragma unroll
  for(int d=0;d<5;++d) rw[d]=(v2f){0.0f,0.0f};
  {
    const float* wb = W12 + lane*2;
    #pragma unroll 2
    for(int f0=0; f0<64; f0+=4){
      const float4 rv = *(const float4*)(Brad + f0);
      #pragma unroll
      for(int d=0;d<5;++d){
        const float* p = wb + (d*4096 + f0*64)*2;
        const v2f w0 = *(const v2f*)(p);
        const v2f w1 = *(const v2f*)(p+128);
        const v2f w2 = *(const v2f*)(p+256);
        const v2f w3 = *(const v2f*)(p+384);
        v2f acc = rw[d];
        acc = fma2(w0,(v2f){rv.x,rv.x},acc);
        acc = fma2(w1,(v2f){rv.y,rv.y},acc);
        acc = fma2(w2,(v2f){rv.z,rv.z},acc);
        acc = fma2(w3,(v2f){rv.w,rv.w},acc);
        rw[d] = acc;
      }
    }
  }

  v2f uv[25];
  {
    // spherical harmonics (wave-uniform scalars), consumed immediately
    const float x2=x*x, y2=y*y, z2=z*z;
    float sh[25];
    sh[0]=0.28209479177387814f;
    sh[1]=0.4886025119029199f*y;
    sh[2]=0.4886025119029199f*z;
    sh[3]=0.4886025119029199f*x;
    sh[4]=1.0925484305920792f*x*y;
    sh[5]=1.0925484305920792f*y*z;
    sh[6]=0.31539156525252005f*(3.0f*z2-1.0f);
    sh[7]=1.0925484305920792f*x*z;
    sh[8]=0.5462742152960396f*(x2-y2);
    sh[9]=0.5900435899266435f*y*(3.0f*x2-y2);
    sh[10]=2.890611442640554f*x*y*z;
    sh[11]=0.4570457994644658f*y*(5.0f*z2-1.0f);
    sh[12]=0.3731763325901154f*z*(5.0f*z2-3.0f);
    sh[13]=0.4570457994644658f*x*(5.0f*z2-1.0f);
    sh[14]=1.445305721320277f*z*(x2-y2);
    sh[15]=0.5900435899266435f*x*(x2-3.0f*y2);
    sh[16]=2.5033429417967046f*x*y*(x2-y2);
    sh[17]=1.7701307697799304f*y*z*(3.0f*x2-y2);
    sh[18]=0.9461746957575601f*x*y*(7.0f*z2-1.0f);
    sh[19]=0.6690465435572892f*y*z*(7.0f*z2-3.0f);
    sh[20]=0.10578554691520431f*(35.0f*z2*z2-30.0f*z2+3.0f);
    sh[21]=0.6690465435572892f*x*z*(7.0f*z2-3.0f);
    sh[22]=0.47308734787878004f*(x2-y2)*(7.0f*z2-1.0f);
    sh[23]=1.7701307697799304f*x*z*(x2-3.0f*y2);
    sh[24]=0.6258357354491761f*(x2*x2-6.0f*x2*y2+y2*y2);
    #pragma unroll
    for(int lm=0;lm<25;++lm) uv[lm] = rw[DEGA[lm]] * sh[lm];
  }

  float t[25], yn[25];

  // ---- layer 0 CG (uv interleaved: u = .x, v = .y) ----
  #pragma unroll
  for(int i=0;i<25;++i) t[i]=0.0f;
  cg_all<2,2>(wpa, lane, (const float*)uv, ((const float*)uv)+1, t);

  // ---- fused (Woa@W1b, Woa@W2b) dense, per-degree staged (ping-pong) ----
  #pragma unroll
  for(int lm=0;lm<25;++lm) uv[lm]=(v2f){0.0f,0.0f};
  stage_rows<0>(B0,lane,t); dense_uv2_deg<0>(WAB,lane,B0,uv);
  stage_rows<1>(B1,lane,t); dense_uv2_deg<1>(WAB,lane,B1,uv);
  stage_rows<2>(B0,lane,t); dense_uv2_deg<2>(WAB,lane,B0,uv);
  stage_rows<3>(B1,lane,t); dense_uv2_deg<3>(WAB,lane,B1,uv);
  stage_rows<4>(B0,lane,t); dense_uv2_deg<4>(WAB,lane,B0,uv);

  // ---- layer 1 CG + twt-folded Wout (per-degree staged) ----
  #pragma unroll
  for(int i=0;i<25;++i) t[i]=0.0f;
  cg_all<2,2>(wpb, lane, (const float*)uv, ((const float*)uv)+1, t);
  #pragma unroll
  for(int lm=0;lm<25;++lm) yn[lm]=0.0f;
  stage_rows<0>(B1,lane,t); dense_out1_deg<0>(WO,lane,B1,yn);
  stage_rows<1>(B0,lane,t); dense_out1_deg<1>(WO,lane,B0,yn);
  stage_rows<2>(B1,lane,t); dense_out1_deg<2>(WO,lane,B1,yn);
  stage_rows<3>(B0,lane,t); dense_out1_deg<3>(WO,lane,B0,yn);
  stage_rows<4>(B1,lane,t); dense_out1_deg<4>(WO,lane,B1,yn);

  // ---- scale + segment-sum ----
  if(active){
    const int Zi = an[ai];
    const float a = Atab[Zi*64+lane];
    float* o = out + (size_t)ai*1600 + lane;
    #pragma unroll
    for(int lm=0;lm<25;++lm){
      atomicAdd(o + lm*64, yn[lm]*a);
    }
  }
}

// Fallback (R10 readlane structure, un-fused weights) — used only if ws too small.
__global__ __launch_bounds__(256)
void edge_kernel_fb(
    const int* __restrict__ an, const int* __restrict__ nbr, const float* __restrict__ disp,
    const float* __restrict__ Wrad,
    const float* __restrict__ W1a, const float* __restrict__ W2a,
    const float* __restrict__ wpa, const float* __restrict__ Woa,
    const float* __restrict__ W1b, const float* __restrict__ W2b,
    const float* __restrict__ wpb, const float* __restrict__ Wob,
    const float* __restrict__ twt, const float* __restrict__ Atab,
    float* __restrict__ out, int NE)
{
  const int lane = threadIdx.x & 63;
  const int w    = threadIdx.x >> 6;
  const int e0   = blockIdx.x*4 + w;
  const bool active = e0 < NE;
  const int e = active ? e0 : 0;

  const int ai = nbr[2*e];
  const int aj = nbr[2*e+1];
  const float dx = disp[3*e], dy = disp[3*e+1], dz = disp[3*e+2];
  const float r  = sqrtf(fmaf(dx,dx,fmaf(dy,dy,dz*dz)) + 1e-12f);
  const float ir = 1.0f/r;
  const float x = dx*ir, y = dy*ir, z = dz*ir;
  const float fc = (r < 5.0f) ? (0.5f*(cosf(0.62831853071795864769f*r)+1.0f)) : 0.0f;

  const int Zj = an[aj];
  const float* Wr = Wrad + Zj*1024 + lane;
  float rad = 0.0f;
  #pragma unroll
  for(int k=0;k<16;++k){
    const float d  = r - (float)k*(1.0f/3.0f);
    const float rb = __expf(-10.24f*d*d)*fc;
    rad = fmaf(rb, Wr[k*64], rad);
  }

  float rw1[5], rw2[5];
  #pragma unroll
  for(int d=0;d<5;++d){ rw1[d]=0.0f; rw2[d]=0.0f; }
  {
    const float* w1b = W1a + lane;
    const float* w2b = W2a + lane;
    #pragma unroll 2
    for(int f=0; f<64; ++f){
      const float rf = rdl(rad, f);
      #pragma unroll
      for(int d=0;d<5;++d){
        rw1[d] = fmaf(rf, w1b[d*4096 + f*64], rw1[d]);
        rw2[d] = fmaf(rf, w2b[d*4096 + f*64], rw2[d]);
      }
    }
  }

  float u[25], v[25];
  {
    const float x2=x*x, y2=y*y, z2=z*z;
    float sh[25];
    sh[0]=0.28209479177387814f;
    sh[1]=0.4886025119029199f*y;
    sh[2]=0.4886025119029199f*z;
    sh[3]=0.4886025119029199f*x;
    sh[4]=1.0925484305920792f*x*y;
    sh[5]=1.0925484305920792f*y*z;
    sh[6]=0.31539156525252005f*(3.0f*z2-1.0f);
    sh[7]=1.0925484305920792f*x*z;
    sh[8]=0.5462742152960396f*(x2-y2);
    sh[9]=0.5900435899266435f*y*(3.0f*x2-y2);
    sh[10]=2.890611442640554f*x*y*z;
    sh[11]=0.4570457994644658f*y*(5.0f*z2-1.0f);
    sh[12]=0.3731763325901154f*z*(5.0f*z2-3.0f);
    sh[13]=0.4570457994644658f*x*(5.0f*z2-1.0f);
    sh[14]=1.445305721320277f*z*(x2-y2);
    sh[15]=0.5900435899266435f*x*(x2-3.0f*y2);
    sh[16]=2.5033429417967046f*x*y*(x2-y2);
    sh[17]=1.7701307697799304f*y*z*(3.0f*x2-y2);
    sh[18]=0.9461746957575601f*x*y*(7.0f*z2-1.0f);
    sh[19]=0.6690465435572892f*y*z*(7.0f*z2-3.0f);
    sh[20]=0.10578554691520431f*(35.0f*z2*z2-30.0f*z2+3.0f);
    sh[21]=0.6690465435572892f*x*z*(7.0f*z2-3.0f);
    sh[22]=0.47308734787878004f*(x2-y2)*(7.0f*z2-1.0f);
    sh[23]=1.7701307697799304f*x*z*(x2-3.0f*y2);
    sh[24]=0.6258357354491761f*(x2*x2-6.0f*x2*y2+y2*y2);
    #pragma unroll
    for(int lm=0;lm<25;++lm){
      u[lm] = sh[lm]*rw1[DEGA[lm]];
      v[lm] = sh[lm]*rw2[DEGA[lm]];
    }
  }

  float t[25], yn[25];
  #pragma unroll
  for(int i=0;i<25;++i) t[i]=0.0f;
  cg_all<1,1>(wpa, lane, u, v, t);
  {
    #pragma unroll
    for(int lm=0;lm<25;++lm) yn[lm]=0.0f;
    const float* wb = Woa + lane;
    #pragma unroll 2
    for(int f=0; f<64; ++f){
      float wv[5];
      #pragma unroll
      for(int d=0;d<5;++d) wv[d] = wb[d*4096 + f*64];
      #pragma unroll
      for(int lm=0;lm<25;++lm) yn[lm] = fmaf(rdl(t[lm], f), wv[DEGA[lm]], yn[lm]);
    }
  }
  {
    #pragma unroll
    for(int lm=0;lm<25;++lm){ u[lm]=0.0f; v[lm]=0.0f; }
    const float* w1b = W1b + lane;
    const float* w2b = W2b + lane;
    #pragma unroll 2
    for(int f=0; f<64; ++f){
      float w1[5], w2[5];
      #pragma unroll
      for(int d=0;d<5;++d){ w1[d] = w1b[d*4096 + f*64]; w2[d] = w2b[d*4096 + f*64]; }
      #pragma unroll
      for(int lm=0;lm<25;++lm){
        const float yf = rdl(yn[lm], f);
        u[lm] = fmaf(yf, w1[DEGA[lm]], u[lm]);
        v[lm] = fmaf(yf, w2[DEGA[lm]], v[lm]);
      }
    }
  }
  #pragma unroll
  for(int i=0;i<25;++i) t[i]=0.0f;
  cg_all<1,1>(wpb, lane, u, v, t);
  {
    #pragma unroll
    for(int lm=0;lm<25;++lm) yn[lm]=0.0f;
    const float* wb = Wob + lane;
    #pragma unroll 2
    for(int f=0; f<64; ++f){
      float wv[5];
      #pragma unroll
      for(int d=0;d<5;++d) wv[d] = wb[d*4096 + f*64];
      #pragma unroll
      for(int lm=0;lm<25;++lm) yn[lm] = fmaf(rdl(t[lm], f), wv[DEGA[lm]], yn[lm]);
    }
  }

  if(active){
    const int Zi = an[ai];
    const float a = Atab[Zi*64+lane];
    float s[5];
    #pragma unroll
    for(int d=0;d<5;++d) s[d] = a*twt[d*64+lane];
    float* o = out + (size_t)ai*1600 + lane;
    #pragma unroll
    for(int lm=0;lm<25;++lm){
      atomicAdd(o + lm*64, yn[lm]*s[DEGA[lm]]);
    }
  }
}

// ---------------------------------------------------------------------------
extern "C" void kernel_launch(void* const* d_in, const int* in_sizes, int n_in,
                              void* d_out, int out_size, void* d_ws, size_t ws_size,
                              hipStream_t stream)
{
  const int*   an   = (const int*)  d_in[0];
  const int*   nbr  = (const int*)  d_in[1];
  const float* disp = (const float*)d_in[2];
  const float* emb  = (const float*)d_in[3];
  const float* Wemb = (const float*)d_in[4];
  const float* Wrad = (const float*)d_in[5];
  const float* W1a  = (const float*)d_in[6];
  const float* W2a  = (const float*)d_in[7];
  const float* wpa  = (const float*)d_in[8];
  const float* Woa  = (const float*)d_in[9];
  const float* W1b  = (const float*)d_in[10];
  const float* W2b  = (const float*)d_in[11];
  const float* wpb  = (const float*)d_in[12];
  const float* Wob  = (const float*)d_in[13];
  const float* twt  = (const float*)d_in[14];

  const int NA = in_sizes[0];
  const int NE = in_sizes[1]/2;
  const int NS = in_sizes[3]/64;

  float* out = (float*)d_out;
  hipMemsetAsync(out, 0, (size_t)out_size*sizeof(float), stream);

  // ws layout: W12[40960] | WAB[40960] | WO[20480] | Atab[NS*64]
  const size_t need = (size_t)(40960 + 40960 + 20480 + NS*64) * sizeof(float);
  if(ws_size >= need){
    float* W12  = (float*)d_ws;
    float* WAB  = W12 + 40960;
    float* WO   = WAB + 40960;
    float* Atab = WO  + 20480;
    wfuse_kernel<<<80, 256, 0, stream>>>(W1a,W2a,Woa,W1b,W2b,Wob,twt,W12,WAB,WO);
    atab_kernel<<<NS, 64, 0, stream>>>(emb, Wemb, Atab);
    edge_kernel<<<(NE+3)/4, 256, 0, stream>>>(an, nbr, disp, Wrad,
                                              W12, WAB, wpa, wpb, WO,
                                              Atab, out, NE);
    self_kernel<<<(NA*64+255)/256, 256, 0, stream>>>(an, Atab, out, NA);
  } else {
    float* Atab = (float*)d_ws;
    atab_kernel<<<NS, 64, 0, stream>>>(emb, Wemb, Atab);
    edge_kernel_fb<<<(NE+3)/4, 256, 0, stream>>>(an, nbr, disp, Wrad,
                                                 W1a, W2a, wpa, Woa,
                                                 W1b, W2b, wpb, Wob,
                                                 twt, Atab, out, NE);
    self_kernel<<<(NA*64+255)/256, 256, 0, stream>>>(an, Atab, out, NA);
  }
}

// Round 16
// 1015.228 us; speedup vs baseline: 2.0309x; 2.0309x over previous
//
#include <hip/hip_runtime.h>
#include <array>

#define DEV __device__ __forceinline__

typedef float v2f __attribute__((ext_vector_type(2)));

// ---------------------------------------------------------------------------
// Compile-time real Clebsch-Gordan tables (mirror of reference _build_paths)
// ---------------------------------------------------------------------------
namespace cgt {

constexpr double FACT[14] = {1.,1.,2.,6.,24.,120.,720.,5040.,40320.,362880.,
                             3628800.,39916800.,479001600.,6227020800.};

constexpr double csqrt(double x){
  if(x <= 0.0) return 0.0;
  double g = x > 1.0 ? x : 1.0;
  for(int i=0;i<28;++i) g = 0.5*(g + x/g);
  return g;
}

constexpr double cgc(int l1,int m1,int l2,int m2,int l3,int m3){
  if(m3 != m1+m2) return 0.0;
  double pre = (2.0*l3+1.0)*FACT[l1+l2-l3]*FACT[l1-l2+l3]*FACT[-l1+l2+l3]/FACT[l1+l2+l3+1];
  pre = csqrt(pre * FACT[l1+m1]*FACT[l1-m1]*FACT[l2+m2]*FACT[l2-m2]*FACT[l3+m3]*FACT[l3-m3]);
  double s = 0.0;
  for(int k=0;k<=l1+l2-l3;++k){
    int d1=l1+l2-l3-k, d2=l1-m1-k, d3=l2+m2-k, d4=l3-l2+m1+k, d5=l3-l1-m2+k;
    if(d1<0||d2<0||d3<0||d4<0||d5<0) continue;
    double den = FACT[k]*FACT[d1]*FACT[d2]*FACT[d3]*FACT[d4]*FACT[d5];
    s += ((k&1)? -1.0 : 1.0)/den;
  }
  return pre*s;
}

struct C2 { double re, im; };

// U_l[a, m+l] of the complex->real SH change of basis
constexpr C2 uent(int l, int a, int m){
  const double s = 0.70710678118654752440;
  int mr = a - l;
  if(mr == 0) return (m==0) ? C2{1.0,0.0} : C2{0.0,0.0};
  if(mr > 0){
    if(m ==  mr) return C2{ (mr&1)? -s : s, 0.0};
    if(m == -mr) return C2{ s, 0.0};
    return C2{0.0,0.0};
  }
  if(m ==  mr) return C2{0.0, s};
  if(m == -mr) return C2{0.0, ((-mr)&1)? s : -s};
  return C2{0.0,0.0};
}

constexpr float crent(int l1,int l2,int l3,int a,int b,int c){
  double re = 0.0;
  int mrc = c - l3;
  for(int i=0;i<2;++i){
    if(i==1 && a==l1) break;
    int m1 = (i==0) ? (a-l1) : (l1-a);
    for(int j=0;j<2;++j){
      if(j==1 && b==l2) break;
      int m2 = (j==0) ? (b-l2) : (l2-b);
      int m3 = m1+m2;
      if(m3 < -l3 || m3 > l3) continue;
      if(m3 != mrc && m3 != -mrc) continue;   // U3 row-c sparsity
      C2 u1 = uent(l1,a,m1), u2 = uent(l2,b,m2), u3 = uent(l3,c,m3);
      double u3re = u3.re, u3im = -u3.im;     // conj
      double pr = u1.re*u2.re - u1.im*u2.im;
      double pi = u1.re*u2.im + u1.im*u2.re;
      double rr = pr*u3re - pi*u3im;          // Re(u1*u2*conj(u3))
      if(rr == 0.0) continue;
      re += rr * cgc(l1,m1,l2,m2,l3,m3);
    }
  }
  return (float)re;
}

template<int L1,int L2,int L3>
constexpr std::array<float,(2*L1+1)*(2*L2+1)*(2*L3+1)> build_path(){
  std::array<float,(2*L1+1)*(2*L2+1)*(2*L3+1)> r{};
  for(int a=0;a<2*L1+1;++a)
    for(int b=0;b<2*L2+1;++b)
      for(int c=0;c<2*L3+1;++c)
        r[(a*(2*L2+1)+b)*(2*L3+1)+c] = crent(L1,L2,L3,a,b,c);
  return r;
}

} // namespace cgt

// ---------------------------------------------------------------------------
// R16 = R12 (best: 1016us, VGPR 64, VALU 68%) + manual software-pipelined
// weight prefetch.  R15's per-degree ping-pong flipped the bimodal allocator
// to 256 VGPR (2 waves/SIMD, 2062us) — reverted.  R12's residual (~30k
// cyc/edge over static) is exposed load latency; the 400KB/edge weight
// stream misses L1 (32KB) every pass -> ~200cyc L2 latency per weight
// load, serialized by the unroll-1 bodies.  Fix: rotate next-iteration's
// weight registers manually — issue w_next loads BEFORE the FMA block
// consuming w_cur.  The +2KB over-read past each weight slice lands in the
// adjacent ws region (inside the checked allocation — safe, values unused).
// ---------------------------------------------------------------------------
__device__ constexpr int DEGA[25] = {0,1,1,1,2,2,2,2,2,3,3,3,3,3,3,3,4,4,4,4,4,4,4,4,4};

DEV v2f fma2(v2f a, v2f b, v2f c){
#if __has_builtin(__builtin_elementwise_fma)
  return __builtin_elementwise_fma(a,b,c);
#else
  return (v2f){fmaf(a.x,b.x,c.x), fmaf(a.y,b.y,c.y)};
#endif
}

DEV float rdl(float v, int l){   // fallback kernel only
  return __int_as_float(__builtin_amdgcn_readlane(__float_as_int(v), l));
}

// One CG path; u,v accessed with compile-time strides (US/VS).
template<int L1,int L2,int L3,int P,int US,int VS>
DEV void cg_path(const float* __restrict__ wp, int lane,
                 const float* __restrict__ u, const float* __restrict__ v,
                 float* __restrict__ t){
  constexpr auto C = cgt::build_path<L1,L2,L3>();
  const float wpv = wp[P*64 + lane];
  #pragma unroll
  for(int a=0;a<2*L1+1;++a){
    #pragma unroll
    for(int b=0;b<2*L2+1;++b){
      float uvw = 0.0f; bool made = false;
      #pragma unroll
      for(int c=0;c<2*L3+1;++c){
        const float cv = C[(a*(2*L2+1)+b)*(2*L3+1)+c];
        if(cv != 0.0f){
          if(!made){ uvw = u[(L1*L1+a)*US]*v[(L2*L2+b)*VS]*wpv; made = true; }
          t[L3*L3+c] = fmaf(cv, uvw, t[L3*L3+c]);
        }
      }
    }
  }
}

template<int US,int VS>
DEV void cg_all(const float* __restrict__ wp, int lane,
                const float* __restrict__ u, const float* __restrict__ v,
                float* __restrict__ t){
  cg_path<0,0,0,0,US,VS>(wp,lane,u,v,t);  cg_path<0,1,1,1,US,VS>(wp,lane,u,v,t);
  cg_path<0,2,2,2,US,VS>(wp,lane,u,v,t);  cg_path<0,3,3,3,US,VS>(wp,lane,u,v,t);
  cg_path<0,4,4,4,US,VS>(wp,lane,u,v,t);
  cg_path<1,0,1,5,US,VS>(wp,lane,u,v,t);  cg_path<1,1,0,6,US,VS>(wp,lane,u,v,t);
  cg_path<1,1,2,7,US,VS>(wp,lane,u,v,t);  cg_path<1,2,1,8,US,VS>(wp,lane,u,v,t);
  cg_path<1,2,3,9,US,VS>(wp,lane,u,v,t);  cg_path<1,3,2,10,US,VS>(wp,lane,u,v,t);
  cg_path<1,3,4,11,US,VS>(wp,lane,u,v,t); cg_path<1,4,3,12,US,VS>(wp,lane,u,v,t);
  cg_path<2,0,2,13,US,VS>(wp,lane,u,v,t); cg_path<2,1,1,14,US,VS>(wp,lane,u,v,t);
  cg_path<2,1,3,15,US,VS>(wp,lane,u,v,t); cg_path<2,2,0,16,US,VS>(wp,lane,u,v,t);
  cg_path<2,2,2,17,US,VS>(wp,lane,u,v,t); cg_path<2,2,4,18,US,VS>(wp,lane,u,v,t);
  cg_path<2,3,1,19,US,VS>(wp,lane,u,v,t); cg_path<2,3,3,20,US,VS>(wp,lane,u,v,t);
  cg_path<2,4,2,21,US,VS>(wp,lane,u,v,t); cg_path<2,4,4,22,US,VS>(wp,lane,u,v,t);
  cg_path<3,0,3,23,US,VS>(wp,lane,u,v,t); cg_path<3,1,2,24,US,VS>(wp,lane,u,v,t);
  cg_path<3,1,4,25,US,VS>(wp,lane,u,v,t); cg_path<3,2,1,26,US,VS>(wp,lane,u,v,t);
  cg_path<3,2,3,27,US,VS>(wp,lane,u,v,t); cg_path<3,3,0,28,US,VS>(wp,lane,u,v,t);
  cg_path<3,3,2,29,US,VS>(wp,lane,u,v,t); cg_path<3,3,4,30,US,VS>(wp,lane,u,v,t);
  cg_path<3,4,1,31,US,VS>(wp,lane,u,v,t); cg_path<3,4,3,32,US,VS>(wp,lane,u,v,t);
  cg_path<4,0,4,33,US,VS>(wp,lane,u,v,t); cg_path<4,1,3,34,US,VS>(wp,lane,u,v,t);
  cg_path<4,2,2,35,US,VS>(wp,lane,u,v,t); cg_path<4,2,4,36,US,VS>(wp,lane,u,v,t);
  cg_path<4,3,1,37,US,VS>(wp,lane,u,v,t); cg_path<4,3,3,38,US,VS>(wp,lane,u,v,t);
  cg_path<4,4,0,39,US,VS>(wp,lane,u,v,t); cg_path<4,4,2,40,US,VS>(wp,lane,u,v,t);
  cg_path<4,4,4,41,US,VS>(wp,lane,u,v,t);
}

// Degree-D packed dense with 1-deep weight prefetch:
// uv[lm] += sum_f Bt[lm][f]*(WA,WB)[D][f][g].  Bt = full [25][64] staging.
template<int D>
DEV void dense_uv2_deg(const float* __restrict__ Wint, int lane,
                       const float* __restrict__ Bt, v2f* __restrict__ uv){
  constexpr int L0 = D*D, N = 2*D+1;
  const float* p = Wint + lane*2 + D*8192;      // (D*4096)*2
  v2f w0 = *(const v2f*)(p);
  v2f w1 = *(const v2f*)(p+128);
  v2f w2 = *(const v2f*)(p+256);
  v2f w3 = *(const v2f*)(p+384);
  #pragma unroll 1
  for(int f0=0; f0<64; f0+=4){
    const float* pn = p + 512;                  // next f-chunk (over-reads 2KB
    v2f n0 = *(const v2f*)(pn);                 //  past slice end on last iter:
    v2f n1 = *(const v2f*)(pn+128);             //  lands in adjacent ws region)
    v2f n2 = *(const v2f*)(pn+256);
    v2f n3 = *(const v2f*)(pn+384);
    #pragma unroll
    for(int m=0;m<N;++m){
      const float4 tv = *(const float4*)(Bt + (L0+m)*64 + f0);
      v2f acc = uv[L0+m];
      acc = fma2(w0,(v2f){tv.x,tv.x},acc);
      acc = fma2(w1,(v2f){tv.y,tv.y},acc);
      acc = fma2(w2,(v2f){tv.z,tv.z},acc);
      acc = fma2(w3,(v2f){tv.w,tv.w},acc);
      uv[L0+m] = acc;
    }
    w0=n0; w1=n1; w2=n2; w3=n3; p = pn;
  }
}

// Degree-D scalar out dense with 1-deep weight prefetch.
template<int D>
DEV void dense_out1_deg(const float* __restrict__ W, int lane,
                        const float* __restrict__ Bt, float* __restrict__ yn){
  constexpr int L0 = D*D, N = 2*D+1;
  const float* p = W + lane + D*4096;
  float w0 = p[0], w1 = p[64], w2 = p[128], w3 = p[192];
  #pragma unroll 1
  for(int f0=0; f0<64; f0+=4){
    const float* pn = p + 256;
    float n0 = pn[0], n1 = pn[64], n2 = pn[128], n3 = pn[192];
    #pragma unroll
    for(int m=0;m<N;++m){
      const float4 tv = *(const float4*)(Bt + (L0+m)*64 + f0);
      float acc = yn[L0+m];
      acc = fmaf(tv.x,w0,acc);
      acc = fmaf(tv.y,w1,acc);
      acc = fmaf(tv.z,w2,acc);
      acc = fmaf(tv.w,w3,acc);
      yn[L0+m] = acc;
    }
    w0=n0; w1=n1; w2=n2; w3=n3; p = pn;
  }
}

// ---------------------------------------------------------------------------
// Kernels
// ---------------------------------------------------------------------------
// Precompute: W12 = interleave(W1a,W2a); WAB = interleave(Woa@W1b, Woa@W2b);
// WO = Wob * twt.  One thread per (d,f,g).
__global__ void wfuse_kernel(const float* __restrict__ W1a, const float* __restrict__ W2a,
                             const float* __restrict__ Woa, const float* __restrict__ W1b,
                             const float* __restrict__ W2b, const float* __restrict__ Wob,
                             const float* __restrict__ twt,
                             float* __restrict__ W12, float* __restrict__ WAB,
                             float* __restrict__ WO){
  const int i = blockIdx.x*256 + threadIdx.x;   // 0 .. 20479
  if(i >= 20480) return;
  const int d = i >> 12, rem = i & 4095, f = rem >> 6, g = rem & 63;
  W12[2*i+0] = W1a[i];
  W12[2*i+1] = W2a[i];
  const float* wo  = Woa + d*4096 + f*64;   // row f: [h]
  const float* wb1 = W1b + d*4096 + g;      // col g: [h][g] stride 64
  const float* wb2 = W2b + d*4096 + g;
  float sa = 0.0f, sb = 0.0f;
  for(int h=0; h<64; ++h){
    const float a = wo[h];
    sa = fmaf(a, wb1[h*64], sa);
    sb = fmaf(a, wb2[h*64], sb);
  }
  WAB[2*i+0] = sa;
  WAB[2*i+1] = sb;
  WO[i] = Wob[i] * twt[d*64 + g];
}

// A[s][g] = emb_table[s] @ W_emb_t  (species-deduped edge scale table)
__global__ void atab_kernel(const float* __restrict__ emb, const float* __restrict__ Wemb,
                            float* __restrict__ A){
  const int s = blockIdx.x;
  const int g = threadIdx.x;
  float acc = 0.0f;
  for(int f=0; f<64; ++f) acc = fmaf(emb[s*64+f], Wemb[f*64+g], acc);
  A[s*64+g] = acc;
}

// out[a,0,:] += A[Z[a]]
__global__ void self_kernel(const int* __restrict__ an, const float* __restrict__ A,
                            float* __restrict__ out, int NA){
  const int i = blockIdx.x*256 + threadIdx.x;
  if(i < NA*64){
    const int a = i>>6, g = i&63;
    out[(size_t)a*1600 + g] += A[an[a]*64 + g];
  }
}

// Fused edge kernel: one wave per edge (lane = feature g).
// Wave-private LDS slice (1600 t-staging + 64 rad), no barriers.  (R12 layout)
__global__ __launch_bounds__(256)
void edge_kernel(
    const int* __restrict__ an, const int* __restrict__ nbr, const float* __restrict__ disp,
    const float* __restrict__ Wrad,
    const float* __restrict__ W12, const float* __restrict__ WAB,
    const float* __restrict__ wpa, const float* __restrict__ wpb,
    const float* __restrict__ WO, const float* __restrict__ Atab,
    float* __restrict__ out, int NE)
{
  __shared__ __align__(16) float lds[4*1664];
  const int lane = threadIdx.x & 63;
  const int w    = threadIdx.x >> 6;
  const int e0   = blockIdx.x*4 + w;
  const bool active = e0 < NE;
  const int e = active ? e0 : 0;
  float* Bt   = lds + w*1664;    // [25][64] t staging (wave-private)
  float* Brad = Bt + 1600;       // [64] rad staging

  // ---- radial scalar chain (wave-uniform r) + per-lane rad[f=lane] ----
  const int ai = nbr[2*e];
  const int aj = nbr[2*e+1];
  const float dx = disp[3*e], dy = disp[3*e+1], dz = disp[3*e+2];
  const float r  = sqrtf(fmaf(dx,dx,fmaf(dy,dy,dz*dz)) + 1e-12f);
  const float ir = 1.0f/r;
  const float x = dx*ir, y = dy*ir, z = dz*ir;
  const float fc = (r < 5.0f) ? (0.5f*(cosf(0.62831853071795864769f*r)+1.0f)) : 0.0f;

  const int Zj = an[aj];
  const float* Wr = Wrad + Zj*1024 + lane;
  float rad = 0.0f;
  #pragma unroll
  for(int k=0;k<16;++k){
    const float d  = r - (float)k*(1.0f/3.0f);
    const float rb = __expf(-10.24f*d*d)*fc;
    rad = fmaf(rb, Wr[k*64], rad);
  }
  Brad[lane] = rad;   // same-wave LDS ops are in-order: no barrier needed

  // ---- layer-0 rank-1 collapse with packed (W1a,W2a):
  //      rw[d] = sum_f rad[f] * (W1a,W2a)[d][f][g], rad[f] via LDS broadcast
  v2f rw[5];
  #pragma unroll
  for(int d=0;d<5;++d) rw[d]=(v2f){0.0f,0.0f};
  {
    const float* wb = W12 + lane*2;
    #pragma unroll 1
    for(int f0=0; f0<64; f0+=4){
      const float4 rv = *(const float4*)(Brad + f0);
      #pragma unroll
      for(int d=0;d<5;++d){
        const float* p = wb + (d*4096 + f0*64)*2;
        const v2f w0 = *(const v2f*)(p);
        const v2f w1 = *(const v2f*)(p+128);
        const v2f w2 = *(const v2f*)(p+256);
        const v2f w3 = *(const v2f*)(p+384);
        v2f acc = rw[d];
        acc = fma2(w0,(v2f){rv.x,rv.x},acc);
        acc = fma2(w1,(v2f){rv.y,rv.y},acc);
        acc = fma2(w2,(v2f){rv.z,rv.z},acc);
        acc = fma2(w3,(v2f){rv.w,rv.w},acc);
        rw[d] = acc;
      }
    }
  }

  v2f uv[25];
  {
    // spherical harmonics (wave-uniform scalars), consumed immediately
    const float x2=x*x, y2=y*y, z2=z*z;
    float sh[25];
    sh[0]=0.28209479177387814f;
    sh[1]=0.4886025119029199f*y;
    sh[2]=0.4886025119029199f*z;
    sh[3]=0.4886025119029199f*x;
    sh[4]=1.0925484305920792f*x*y;
    sh[5]=1.0925484305920792f*y*z;
    sh[6]=0.31539156525252005f*(3.0f*z2-1.0f);
    sh[7]=1.0925484305920792f*x*z;
    sh[8]=0.5462742152960396f*(x2-y2);
    sh[9]=0.5900435899266435f*y*(3.0f*x2-y2);
    sh[10]=2.890611442640554f*x*y*z;
    sh[11]=0.4570457994644658f*y*(5.0f*z2-1.0f);
    sh[12]=0.3731763325901154f*z*(5.0f*z2-3.0f);
    sh[13]=0.4570457994644658f*x*(5.0f*z2-1.0f);
    sh[14]=1.445305721320277f*z*(x2-y2);
    sh[15]=0.5900435899266435f*x*(x2-3.0f*y2);
    sh[16]=2.5033429417967046f*x*y*(x2-y2);
    sh[17]=1.7701307697799304f*y*z*(3.0f*x2-y2);
    sh[18]=0.9461746957575601f*x*y*(7.0f*z2-1.0f);
    sh[19]=0.6690465435572892f*y*z*(7.0f*z2-3.0f);
    sh[20]=0.10578554691520431f*(35.0f*z2*z2-30.0f*z2+3.0f);
    sh[21]=0.6690465435572892f*x*z*(7.0f*z2-3.0f);
    sh[22]=0.47308734787878004f*(x2-y2)*(7.0f*z2-1.0f);
    sh[23]=1.7701307697799304f*x*z*(x2-3.0f*y2);
    sh[24]=0.6258357354491761f*(x2*x2-6.0f*x2*y2+y2*y2);
    #pragma unroll
    for(int lm=0;lm<25;++lm) uv[lm] = rw[DEGA[lm]] * sh[lm];
  }

  float t[25], yn[25];

  // ---- layer 0 CG (uv interleaved: u = .x, v = .y) ----
  #pragma unroll
  for(int i=0;i<25;++i) t[i]=0.0f;
  cg_all<2,2>(wpa, lane, (const float*)uv, ((const float*)uv)+1, t);

  // ---- stage t0, fused (Woa@W1b, Woa@W2b) dense via LDS broadcasts ----
  #pragma unroll
  for(int lm=0;lm<25;++lm) Bt[lm*64+lane] = t[lm];
  #pragma unroll
  for(int lm=0;lm<25;++lm) uv[lm]=(v2f){0.0f,0.0f};
  dense_uv2_deg<0>(WAB, lane, Bt, uv);
  dense_uv2_deg<1>(WAB, lane, Bt, uv);
  dense_uv2_deg<2>(WAB, lane, Bt, uv);
  dense_uv2_deg<3>(WAB, lane, Bt, uv);
  dense_uv2_deg<4>(WAB, lane, Bt, uv);

  // ---- layer 1 CG + twt-folded Wout (LDS broadcasts) ----
  #pragma unroll
  for(int i=0;i<25;++i) t[i]=0.0f;
  cg_all<2,2>(wpb, lane, (const float*)uv, ((const float*)uv)+1, t);
  #pragma unroll
  for(int lm=0;lm<25;++lm) Bt[lm*64+lane] = t[lm];
  #pragma unroll
  for(int lm=0;lm<25;++lm) yn[lm]=0.0f;
  dense_out1_deg<0>(WO, lane, Bt, yn);
  dense_out1_deg<1>(WO, lane, Bt, yn);
  dense_out1_deg<2>(WO, lane, Bt, yn);
  dense_out1_deg<3>(WO, lane, Bt, yn);
  dense_out1_deg<4>(WO, lane, Bt, yn);

  // ---- scale + segment-sum ----
  if(active){
    const int Zi = an[ai];
    const float a = Atab[Zi*64+lane];
    float* o = out + (size_t)ai*1600 + lane;
    #pragma unroll
    for(int lm=0;lm<25;++lm){
      atomicAdd(o + lm*64, yn[lm]*a);
    }
  }
}

// Fallback (R10 readlane structure, un-fused weights) — used only if ws too small.
__global__ __launch_bounds__(256)
void edge_kernel_fb(
    const int* __restrict__ an, const int* __restrict__ nbr, const float* __restrict__ disp,
    const float* __restrict__ Wrad,
    const float* __restrict__ W1a, const float* __restrict__ W2a,
    const float* __restrict__ wpa, const float* __restrict__ Woa,
    const float* __restrict__ W1b, const float* __restrict__ W2b,
    const float* __restrict__ wpb, const float* __restrict__ Wob,
    const float* __restrict__ twt, const float* __restrict__ Atab,
    float* __restrict__ out, int NE)
{
  const int lane = threadIdx.x & 63;
  const int w    = threadIdx.x >> 6;
  const int e0   = blockIdx.x*4 + w;
  const bool active = e0 < NE;
  const int e = active ? e0 : 0;

  const int ai = nbr[2*e];
  const int aj = nbr[2*e+1];
  const float dx = disp[3*e], dy = disp[3*e+1], dz = disp[3*e+2];
  const float r  = sqrtf(fmaf(dx,dx,fmaf(dy,dy,dz*dz)) + 1e-12f);
  const float ir = 1.0f/r;
  const float x = dx*ir, y = dy*ir, z = dz*ir;
  const float fc = (r < 5.0f) ? (0.5f*(cosf(0.62831853071795864769f*r)+1.0f)) : 0.0f;

  const int Zj = an[aj];
  const float* Wr = Wrad + Zj*1024 + lane;
  float rad = 0.0f;
  #pragma unroll
  for(int k=0;k<16;++k){
    const float d  = r - (float)k*(1.0f/3.0f);
    const float rb = __expf(-10.24f*d*d)*fc;
    rad = fmaf(rb, Wr[k*64], rad);
  }

  float rw1[5], rw2[5];
  #pragma unroll
  for(int d=0;d<5;++d){ rw1[d]=0.0f; rw2[d]=0.0f; }
  {
    const float* w1b = W1a + lane;
    const float* w2b = W2a + lane;
    #pragma unroll 2
    for(int f=0; f<64; ++f){
      const float rf = rdl(rad, f);
      #pragma unroll
      for(int d=0;d<5;++d){
        rw1[d] = fmaf(rf, w1b[d*4096 + f*64], rw1[d]);
        rw2[d] = fmaf(rf, w2b[d*4096 + f*64], rw2[d]);
      }
    }
  }

  float u[25], v[25];
  {
    const float x2=x*x, y2=y*y, z2=z*z;
    float sh[25];
    sh[0]=0.28209479177387814f;
    sh[1]=0.4886025119029199f*y;
    sh[2]=0.4886025119029199f*z;
    sh[3]=0.4886025119029199f*x;
    sh[4]=1.0925484305920792f*x*y;
    sh[5]=1.0925484305920792f*y*z;
    sh[6]=0.31539156525252005f*(3.0f*z2-1.0f);
    sh[7]=1.0925484305920792f*x*z;
    sh[8]=0.5462742152960396f*(x2-y2);
    sh[9]=0.5900435899266435f*y*(3.0f*x2-y2);
    sh[10]=2.890611442640554f*x*y*z;
    sh[11]=0.4570457994644658f*y*(5.0f*z2-1.0f);
    sh[12]=0.3731763325901154f*z*(5.0f*z2-3.0f);
    sh[13]=0.4570457994644658f*x*(5.0f*z2-1.0f);
    sh[14]=1.445305721320277f*z*(x2-y2);
    sh[15]=0.5900435899266435f*x*(x2-3.0f*y2);
    sh[16]=2.5033429417967046f*x*y*(x2-y2);
    sh[17]=1.7701307697799304f*y*z*(3.0f*x2-y2);
    sh[18]=0.9461746957575601f*x*y*(7.0f*z2-1.0f);
    sh[19]=0.6690465435572892f*y*z*(7.0f*z2-3.0f);
    sh[20]=0.10578554691520431f*(35.0f*z2*z2-30.0f*z2+3.0f);
    sh[21]=0.6690465435572892f*x*z*(7.0f*z2-3.0f);
    sh[22]=0.47308734787878004f*(x2-y2)*(7.0f*z2-1.0f);
    sh[23]=1.7701307697799304f*x*z*(x2-3.0f*y2);
    sh[24]=0.6258357354491761f*(x2*x2-6.0f*x2*y2+y2*y2);
    #pragma unroll
    for(int lm=0;lm<25;++lm){
      u[lm] = sh[lm]*rw1[DEGA[lm]];
      v[lm] = sh[lm]*rw2[DEGA[lm]];
    }
  }

  float t[25], yn[25];
  #pragma unroll
  for(int i=0;i<25;++i) t[i]=0.0f;
  cg_all<1,1>(wpa, lane, u, v, t);
  {
    #pragma unroll
    for(int lm=0;lm<25;++lm) yn[lm]=0.0f;
    const float* wb = Woa + lane;
    #pragma unroll 2
    for(int f=0; f<64; ++f){
      float wv[5];
      #pragma unroll
      for(int d=0;d<5;++d) wv[d] = wb[d*4096 + f*64];
      #pragma unroll
      for(int lm=0;lm<25;++lm) yn[lm] = fmaf(rdl(t[lm], f), wv[DEGA[lm]], yn[lm]);
    }
  }
  {
    #pragma unroll
    for(int lm=0;lm<25;++lm){ u[lm]=0.0f; v[lm]=0.0f; }
    const float* w1b = W1b + lane;
    const float* w2b = W2b + lane;
    #pragma unroll 2
    for(int f=0; f<64; ++f){
      float w1[5], w2[5];
      #pragma unroll
      for(int d=0;d<5;++d){ w1[d] = w1b[d*4096 + f*64]; w2[d] = w2b[d*4096 + f*64]; }
      #pragma unroll
      for(int lm=0;lm<25;++lm){
        const float yf = rdl(yn[lm], f);
        u[lm] = fmaf(yf, w1[DEGA[lm]], u[lm]);
        v[lm] = fmaf(yf, w2[DEGA[lm]], v[lm]);
      }
    }
  }
  #pragma unroll
  for(int i=0;i<25;++i) t[i]=0.0f;
  cg_all<1,1>(wpb, lane, u, v, t);
  {
    #pragma unroll
    for(int lm=0;lm<25;++lm) yn[lm]=0.0f;
    const float* wb = Wob + lane;
    #pragma unroll 2
    for(int f=0; f<64; ++f){
      float wv[5];
      #pragma unroll
      for(int d=0;d<5;++d) wv[d] = wb[d*4096 + f*64];
      #pragma unroll
      for(int lm=0;lm<25;++lm) yn[lm] = fmaf(rdl(t[lm], f), wv[DEGA[lm]], yn[lm]);
    }
  }

  if(active){
    const int Zi = an[ai];
    const float a = Atab[Zi*64+lane];
    float s[5];
    #pragma unroll
    for(int d=0;d<5;++d) s[d] = a*twt[d*64+lane];
    float* o = out + (size_t)ai*1600 + lane;
    #pragma unroll
    for(int lm=0;lm<25;++lm){
      atomicAdd(o + lm*64, yn[lm]*s[DEGA[lm]]);
    }
  }
}

// ---------------------------------------------------------------------------
extern "C" void kernel_launch(void* const* d_in, const int* in_sizes, int n_in,
                              void* d_out, int out_size, void* d_ws, size_t ws_size,
                              hipStream_t stream)
{
  const int*   an   = (const int*)  d_in[0];
  const int*   nbr  = (const int*)  d_in[1];
  const float* disp = (const float*)d_in[2];
  const float* emb  = (const float*)d_in[3];
  const float* Wemb = (const float*)d_in[4];
  const float* Wrad = (const float*)d_in[5];
  const float* W1a  = (const float*)d_in[6];
  const float* W2a  = (const float*)d_in[7];
  const float* wpa  = (const float*)d_in[8];
  const float* Woa  = (const float*)d_in[9];
  const float* W1b  = (const float*)d_in[10];
  const float* W2b  = (const float*)d_in[11];
  const float* wpb  = (const float*)d_in[12];
  const float* Wob  = (const float*)d_in[13];
  const float* twt  = (const float*)d_in[14];

  const int NA = in_sizes[0];
  const int NE = in_sizes[1]/2;
  const int NS = in_sizes[3]/64;

  float* out = (float*)d_out;
  hipMemsetAsync(out, 0, (size_t)out_size*sizeof(float), stream);

  // ws layout: W12[40960] | WAB[40960] | WO[20480] | Atab[NS*64]
  // (dense prefetch over-reads <=2KB past each slice: stays inside this block)
  const size_t need = (size_t)(40960 + 40960 + 20480 + NS*64) * sizeof(float);
  if(ws_size >= need){
    float* W12  = (float*)d_ws;
    float* WAB  = W12 + 40960;
    float* WO   = WAB + 40960;
    float* Atab = WO  + 20480;
    wfuse_kernel<<<80, 256, 0, stream>>>(W1a,W2a,Woa,W1b,W2b,Wob,twt,W12,WAB,WO);
    atab_kernel<<<NS, 64, 0, stream>>>(emb, Wemb, Atab);
    edge_kernel<<<(NE+3)/4, 256, 0, stream>>>(an, nbr, disp, Wrad,
                                              W12, WAB, wpa, wpb, WO,
                                              Atab, out, NE);
    self_kernel<<<(NA*64+255)/256, 256, 0, stream>>>(an, Atab, out, NA);
  } else {
    float* Atab = (float*)d_ws;
    atab_kernel<<<NS, 64, 0, stream>>>(emb, Wemb, Atab);
    edge_kernel_fb<<<(NE+3)/4, 256, 0, stream>>>(an, nbr, disp, Wrad,
                                                 W1a, W2a, wpa, Woa,
                                                 W1b, W2b, wpb, Wob,
                                                 twt, Atab, out, NE);
    self_kernel<<<(NA*64+255)/256, 256, 0, stream>>>(an, Atab, out, NA);
  }
}

// Round 17
// 1013.929 us; speedup vs baseline: 2.0335x; 1.0013x over previous
//
#include <hip/hip_runtime.h>
#include <array>

#define DEV __device__ __forceinline__

typedef float v2f __attribute__((ext_vector_type(2)));

// ---------------------------------------------------------------------------
// Compile-time real Clebsch-Gordan tables (mirror of reference _build_paths)
// ---------------------------------------------------------------------------
namespace cgt {

constexpr double FACT[14] = {1.,1.,2.,6.,24.,120.,720.,5040.,40320.,362880.,
                             3628800.,39916800.,479001600.,6227020800.};

constexpr double csqrt(double x){
  if(x <= 0.0) return 0.0;
  double g = x > 1.0 ? x : 1.0;
  for(int i=0;i<28;++i) g = 0.5*(g + x/g);
  return g;
}

constexpr double cgc(int l1,int m1,int l2,int m2,int l3,int m3){
  if(m3 != m1+m2) return 0.0;
  double pre = (2.0*l3+1.0)*FACT[l1+l2-l3]*FACT[l1-l2+l3]*FACT[-l1+l2+l3]/FACT[l1+l2+l3+1];
  pre = csqrt(pre * FACT[l1+m1]*FACT[l1-m1]*FACT[l2+m2]*FACT[l2-m2]*FACT[l3+m3]*FACT[l3-m3]);
  double s = 0.0;
  for(int k=0;k<=l1+l2-l3;++k){
    int d1=l1+l2-l3-k, d2=l1-m1-k, d3=l2+m2-k, d4=l3-l2+m1+k, d5=l3-l1-m2+k;
    if(d1<0||d2<0||d3<0||d4<0||d5<0) continue;
    double den = FACT[k]*FACT[d1]*FACT[d2]*FACT[d3]*FACT[d4]*FACT[d5];
    s += ((k&1)? -1.0 : 1.0)/den;
  }
  return pre*s;
}

struct C2 { double re, im; };

// U_l[a, m+l] of the complex->real SH change of basis
constexpr C2 uent(int l, int a, int m){
  const double s = 0.70710678118654752440;
  int mr = a - l;
  if(mr == 0) return (m==0) ? C2{1.0,0.0} : C2{0.0,0.0};
  if(mr > 0){
    if(m ==  mr) return C2{ (mr&1)? -s : s, 0.0};
    if(m == -mr) return C2{ s, 0.0};
    return C2{0.0,0.0};
  }
  if(m ==  mr) return C2{0.0, s};
  if(m == -mr) return C2{0.0, ((-mr)&1)? s : -s};
  return C2{0.0,0.0};
}

constexpr float crent(int l1,int l2,int l3,int a,int b,int c){
  double re = 0.0;
  int mrc = c - l3;
  for(int i=0;i<2;++i){
    if(i==1 && a==l1) break;
    int m1 = (i==0) ? (a-l1) : (l1-a);
    for(int j=0;j<2;++j){
      if(j==1 && b==l2) break;
      int m2 = (j==0) ? (b-l2) : (l2-b);
      int m3 = m1+m2;
      if(m3 < -l3 || m3 > l3) continue;
      if(m3 != mrc && m3 != -mrc) continue;   // U3 row-c sparsity
      C2 u1 = uent(l1,a,m1), u2 = uent(l2,b,m2), u3 = uent(l3,c,m3);
      double u3re = u3.re, u3im = -u3.im;     // conj
      double pr = u1.re*u2.re - u1.im*u2.im;
      double pi = u1.re*u2.im + u1.im*u2.re;
      double rr = pr*u3re - pi*u3im;          // Re(u1*u2*conj(u3))
      if(rr == 0.0) continue;
      re += rr * cgc(l1,m1,l2,m2,l3,m3);
    }
  }
  return (float)re;
}

template<int L1,int L2,int L3>
constexpr std::array<float,(2*L1+1)*(2*L2+1)*(2*L3+1)> build_path(){
  std::array<float,(2*L1+1)*(2*L2+1)*(2*L3+1)> r{};
  for(int a=0;a<2*L1+1;++a)
    for(int b=0;b<2*L2+1;++b)
      for(int c=0;c<2*L3+1;++c)
        r[(a*(2*L2+1)+b)*(2*L3+1)+c] = crent(L1,L2,L3,a,b,c);
  return r;
}

} // namespace cgt

// ---------------------------------------------------------------------------
// R17 = R16 structure with 128-thread blocks (2 waves/block).
// R16 (weight prefetch) was NEUTRAL -> global-load latency already hidden;
// residual is exposed-latency at only ~3.5 waves/SIMD (Occupancy 44%) while
// VGPR=64 permits 8.  The 26.6KB/block LDS bound allows 24 waves/CU (75%),
// so the binding constraint appears block-granular.  Halving the block to
// 2 waves (13.3KB LDS/block, up to 12 blocks/CU, 20000 blocks) raises the
// schedulable wave count without touching per-wave code (allocator-safe).
// ---------------------------------------------------------------------------
__device__ constexpr int DEGA[25] = {0,1,1,1,2,2,2,2,2,3,3,3,3,3,3,3,4,4,4,4,4,4,4,4,4};

DEV v2f fma2(v2f a, v2f b, v2f c){
#if __has_builtin(__builtin_elementwise_fma)
  return __builtin_elementwise_fma(a,b,c);
#else
  return (v2f){fmaf(a.x,b.x,c.x), fmaf(a.y,b.y,c.y)};
#endif
}

DEV float rdl(float v, int l){   // fallback kernel only
  return __int_as_float(__builtin_amdgcn_readlane(__float_as_int(v), l));
}

// One CG path; u,v accessed with compile-time strides (US/VS).
template<int L1,int L2,int L3,int P,int US,int VS>
DEV void cg_path(const float* __restrict__ wp, int lane,
                 const float* __restrict__ u, const float* __restrict__ v,
                 float* __restrict__ t){
  constexpr auto C = cgt::build_path<L1,L2,L3>();
  const float wpv = wp[P*64 + lane];
  #pragma unroll
  for(int a=0;a<2*L1+1;++a){
    #pragma unroll
    for(int b=0;b<2*L2+1;++b){
      float uvw = 0.0f; bool made = false;
      #pragma unroll
      for(int c=0;c<2*L3+1;++c){
        const float cv = C[(a*(2*L2+1)+b)*(2*L3+1)+c];
        if(cv != 0.0f){
          if(!made){ uvw = u[(L1*L1+a)*US]*v[(L2*L2+b)*VS]*wpv; made = true; }
          t[L3*L3+c] = fmaf(cv, uvw, t[L3*L3+c]);
        }
      }
    }
  }
}

template<int US,int VS>
DEV void cg_all(const float* __restrict__ wp, int lane,
                const float* __restrict__ u, const float* __restrict__ v,
                float* __restrict__ t){
  cg_path<0,0,0,0,US,VS>(wp,lane,u,v,t);  cg_path<0,1,1,1,US,VS>(wp,lane,u,v,t);
  cg_path<0,2,2,2,US,VS>(wp,lane,u,v,t);  cg_path<0,3,3,3,US,VS>(wp,lane,u,v,t);
  cg_path<0,4,4,4,US,VS>(wp,lane,u,v,t);
  cg_path<1,0,1,5,US,VS>(wp,lane,u,v,t);  cg_path<1,1,0,6,US,VS>(wp,lane,u,v,t);
  cg_path<1,1,2,7,US,VS>(wp,lane,u,v,t);  cg_path<1,2,1,8,US,VS>(wp,lane,u,v,t);
  cg_path<1,2,3,9,US,VS>(wp,lane,u,v,t);  cg_path<1,3,2,10,US,VS>(wp,lane,u,v,t);
  cg_path<1,3,4,11,US,VS>(wp,lane,u,v,t); cg_path<1,4,3,12,US,VS>(wp,lane,u,v,t);
  cg_path<2,0,2,13,US,VS>(wp,lane,u,v,t); cg_path<2,1,1,14,US,VS>(wp,lane,u,v,t);
  cg_path<2,1,3,15,US,VS>(wp,lane,u,v,t); cg_path<2,2,0,16,US,VS>(wp,lane,u,v,t);
  cg_path<2,2,2,17,US,VS>(wp,lane,u,v,t); cg_path<2,2,4,18,US,VS>(wp,lane,u,v,t);
  cg_path<2,3,1,19,US,VS>(wp,lane,u,v,t); cg_path<2,3,3,20,US,VS>(wp,lane,u,v,t);
  cg_path<2,4,2,21,US,VS>(wp,lane,u,v,t); cg_path<2,4,4,22,US,VS>(wp,lane,u,v,t);
  cg_path<3,0,3,23,US,VS>(wp,lane,u,v,t); cg_path<3,1,2,24,US,VS>(wp,lane,u,v,t);
  cg_path<3,1,4,25,US,VS>(wp,lane,u,v,t); cg_path<3,2,1,26,US,VS>(wp,lane,u,v,t);
  cg_path<3,2,3,27,US,VS>(wp,lane,u,v,t); cg_path<3,3,0,28,US,VS>(wp,lane,u,v,t);
  cg_path<3,3,2,29,US,VS>(wp,lane,u,v,t); cg_path<3,3,4,30,US,VS>(wp,lane,u,v,t);
  cg_path<3,4,1,31,US,VS>(wp,lane,u,v,t); cg_path<3,4,3,32,US,VS>(wp,lane,u,v,t);
  cg_path<4,0,4,33,US,VS>(wp,lane,u,v,t); cg_path<4,1,3,34,US,VS>(wp,lane,u,v,t);
  cg_path<4,2,2,35,US,VS>(wp,lane,u,v,t); cg_path<4,2,4,36,US,VS>(wp,lane,u,v,t);
  cg_path<4,3,1,37,US,VS>(wp,lane,u,v,t); cg_path<4,3,3,38,US,VS>(wp,lane,u,v,t);
  cg_path<4,4,0,39,US,VS>(wp,lane,u,v,t); cg_path<4,4,2,40,US,VS>(wp,lane,u,v,t);
  cg_path<4,4,4,41,US,VS>(wp,lane,u,v,t);
}

// Degree-D packed dense with 1-deep weight prefetch:
// uv[lm] += sum_f Bt[lm][f]*(WA,WB)[D][f][g].  Bt = full [25][64] staging.
template<int D>
DEV void dense_uv2_deg(const float* __restrict__ Wint, int lane,
                       const float* __restrict__ Bt, v2f* __restrict__ uv){
  constexpr int L0 = D*D, N = 2*D+1;
  const float* p = Wint + lane*2 + D*8192;      // (D*4096)*2
  v2f w0 = *(const v2f*)(p);
  v2f w1 = *(const v2f*)(p+128);
  v2f w2 = *(const v2f*)(p+256);
  v2f w3 = *(const v2f*)(p+384);
  #pragma unroll 1
  for(int f0=0; f0<64; f0+=4){
    const float* pn = p + 512;                  // next f-chunk (over-reads 2KB
    v2f n0 = *(const v2f*)(pn);                 //  past slice end on last iter:
    v2f n1 = *(const v2f*)(pn+128);             //  lands in adjacent ws region)
    v2f n2 = *(const v2f*)(pn+256);
    v2f n3 = *(const v2f*)(pn+384);
    #pragma unroll
    for(int m=0;m<N;++m){
      const float4 tv = *(const float4*)(Bt + (L0+m)*64 + f0);
      v2f acc = uv[L0+m];
      acc = fma2(w0,(v2f){tv.x,tv.x},acc);
      acc = fma2(w1,(v2f){tv.y,tv.y},acc);
      acc = fma2(w2,(v2f){tv.z,tv.z},acc);
      acc = fma2(w3,(v2f){tv.w,tv.w},acc);
      uv[L0+m] = acc;
    }
    w0=n0; w1=n1; w2=n2; w3=n3; p = pn;
  }
}

// Degree-D scalar out dense with 1-deep weight prefetch.
template<int D>
DEV void dense_out1_deg(const float* __restrict__ W, int lane,
                        const float* __restrict__ Bt, float* __restrict__ yn){
  constexpr int L0 = D*D, N = 2*D+1;
  const float* p = W + lane + D*4096;
  float w0 = p[0], w1 = p[64], w2 = p[128], w3 = p[192];
  #pragma unroll 1
  for(int f0=0; f0<64; f0+=4){
    const float* pn = p + 256;
    float n0 = pn[0], n1 = pn[64], n2 = pn[128], n3 = pn[192];
    #pragma unroll
    for(int m=0;m<N;++m){
      const float4 tv = *(const float4*)(Bt + (L0+m)*64 + f0);
      float acc = yn[L0+m];
      acc = fmaf(tv.x,w0,acc);
      acc = fmaf(tv.y,w1,acc);
      acc = fmaf(tv.z,w2,acc);
      acc = fmaf(tv.w,w3,acc);
      yn[L0+m] = acc;
    }
    w0=n0; w1=n1; w2=n2; w3=n3; p = pn;
  }
}

// ---------------------------------------------------------------------------
// Kernels
// ---------------------------------------------------------------------------
// Precompute: W12 = interleave(W1a,W2a); WAB = interleave(Woa@W1b, Woa@W2b);
// WO = Wob * twt.  One thread per (d,f,g).
__global__ void wfuse_kernel(const float* __restrict__ W1a, const float* __restrict__ W2a,
                             const float* __restrict__ Woa, const float* __restrict__ W1b,
                             const float* __restrict__ W2b, const float* __restrict__ Wob,
                             const float* __restrict__ twt,
                             float* __restrict__ W12, float* __restrict__ WAB,
                             float* __restrict__ WO){
  const int i = blockIdx.x*256 + threadIdx.x;   // 0 .. 20479
  if(i >= 20480) return;
  const int d = i >> 12, rem = i & 4095, f = rem >> 6, g = rem & 63;
  W12[2*i+0] = W1a[i];
  W12[2*i+1] = W2a[i];
  const float* wo  = Woa + d*4096 + f*64;   // row f: [h]
  const float* wb1 = W1b + d*4096 + g;      // col g: [h][g] stride 64
  const float* wb2 = W2b + d*4096 + g;
  float sa = 0.0f, sb = 0.0f;
  for(int h=0; h<64; ++h){
    const float a = wo[h];
    sa = fmaf(a, wb1[h*64], sa);
    sb = fmaf(a, wb2[h*64], sb);
  }
  WAB[2*i+0] = sa;
  WAB[2*i+1] = sb;
  WO[i] = Wob[i] * twt[d*64 + g];
}

// A[s][g] = emb_table[s] @ W_emb_t  (species-deduped edge scale table)
__global__ void atab_kernel(const float* __restrict__ emb, const float* __restrict__ Wemb,
                            float* __restrict__ A){
  const int s = blockIdx.x;
  const int g = threadIdx.x;
  float acc = 0.0f;
  for(int f=0; f<64; ++f) acc = fmaf(emb[s*64+f], Wemb[f*64+g], acc);
  A[s*64+g] = acc;
}

// out[a,0,:] += A[Z[a]]
__global__ void self_kernel(const int* __restrict__ an, const float* __restrict__ A,
                            float* __restrict__ out, int NA){
  const int i = blockIdx.x*256 + threadIdx.x;
  if(i < NA*64){
    const int a = i>>6, g = i&63;
    out[(size_t)a*1600 + g] += A[an[a]*64 + g];
  }
}

// Fused edge kernel: one wave per edge (lane = feature g).
// 2 waves per block: LDS 2x1664 floats = 13312B/block -> up to 12 blocks/CU.
__global__ __launch_bounds__(128)
void edge_kernel(
    const int* __restrict__ an, const int* __restrict__ nbr, const float* __restrict__ disp,
    const float* __restrict__ Wrad,
    const float* __restrict__ W12, const float* __restrict__ WAB,
    const float* __restrict__ wpa, const float* __restrict__ wpb,
    const float* __restrict__ WO, const float* __restrict__ Atab,
    float* __restrict__ out, int NE)
{
  __shared__ __align__(16) float lds[2*1664];
  const int lane = threadIdx.x & 63;
  const int w    = threadIdx.x >> 6;
  const int e0   = blockIdx.x*2 + w;
  const bool active = e0 < NE;
  const int e = active ? e0 : 0;
  float* Bt   = lds + w*1664;    // [25][64] t staging (wave-private)
  float* Brad = Bt + 1600;       // [64] rad staging

  // ---- radial scalar chain (wave-uniform r) + per-lane rad[f=lane] ----
  const int ai = nbr[2*e];
  const int aj = nbr[2*e+1];
  const float dx = disp[3*e], dy = disp[3*e+1], dz = disp[3*e+2];
  const float r  = sqrtf(fmaf(dx,dx,fmaf(dy,dy,dz*dz)) + 1e-12f);
  const float ir = 1.0f/r;
  const float x = dx*ir, y = dy*ir, z = dz*ir;
  const float fc = (r < 5.0f) ? (0.5f*(cosf(0.62831853071795864769f*r)+1.0f)) : 0.0f;

  const int Zj = an[aj];
  const float* Wr = Wrad + Zj*1024 + lane;
  float rad = 0.0f;
  #pragma unroll
  for(int k=0;k<16;++k){
    const float d  = r - (float)k*(1.0f/3.0f);
    const float rb = __expf(-10.24f*d*d)*fc;
    rad = fmaf(rb, Wr[k*64], rad);
  }
  Brad[lane] = rad;   // same-wave LDS ops are in-order: no barrier needed

  // ---- layer-0 rank-1 collapse with packed (W1a,W2a):
  //      rw[d] = sum_f rad[f] * (W1a,W2a)[d][f][g], rad[f] via LDS broadcast
  v2f rw[5];
  #pragma unroll
  for(int d=0;d<5;++d) rw[d]=(v2f){0.0f,0.0f};
  {
    const float* wb = W12 + lane*2;
    #pragma unroll 1
    for(int f0=0; f0<64; f0+=4){
      const float4 rv = *(const float4*)(Brad + f0);
      #pragma unroll
      for(int d=0;d<5;++d){
        const float* p = wb + (d*4096 + f0*64)*2;
        const v2f w0 = *(const v2f*)(p);
        const v2f w1 = *(const v2f*)(p+128);
        const v2f w2 = *(const v2f*)(p+256);
        const v2f w3 = *(const v2f*)(p+384);
        v2f acc = rw[d];
        acc = fma2(w0,(v2f){rv.x,rv.x},acc);
        acc = fma2(w1,(v2f){rv.y,rv.y},acc);
        acc = fma2(w2,(v2f){rv.z,rv.z},acc);
        acc = fma2(w3,(v2f){rv.w,rv.w},acc);
        rw[d] = acc;
      }
    }
  }

  v2f uv[25];
  {
    // spherical harmonics (wave-uniform scalars), consumed immediately
    const float x2=x*x, y2=y*y, z2=z*z;
    float sh[25];
    sh[0]=0.28209479177387814f;
    sh[1]=0.4886025119029199f*y;
    sh[2]=0.4886025119029199f*z;
    sh[3]=0.4886025119029199f*x;
    sh[4]=1.0925484305920792f*x*y;
    sh[5]=1.0925484305920792f*y*z;
    sh[6]=0.31539156525252005f*(3.0f*z2-1.0f);
    sh[7]=1.0925484305920792f*x*z;
    sh[8]=0.5462742152960396f*(x2-y2);
    sh[9]=0.5900435899266435f*y*(3.0f*x2-y2);
    sh[10]=2.890611442640554f*x*y*z;
    sh[11]=0.4570457994644658f*y*(5.0f*z2-1.0f);
    sh[12]=0.3731763325901154f*z*(5.0f*z2-3.0f);
    sh[13]=0.4570457994644658f*x*(5.0f*z2-1.0f);
    sh[14]=1.445305721320277f*z*(x2-y2);
    sh[15]=0.5900435899266435f*x*(x2-3.0f*y2);
    sh[16]=2.5033429417967046f*x*y*(x2-y2);
    sh[17]=1.7701307697799304f*y*z*(3.0f*x2-y2);
    sh[18]=0.9461746957575601f*x*y*(7.0f*z2-1.0f);
    sh[19]=0.6690465435572892f*y*z*(7.0f*z2-3.0f);
    sh[20]=0.10578554691520431f*(35.0f*z2*z2-30.0f*z2+3.0f);
    sh[21]=0.6690465435572892f*x*z*(7.0f*z2-3.0f);
    sh[22]=0.47308734787878004f*(x2-y2)*(7.0f*z2-1.0f);
    sh[23]=1.7701307697799304f*x*z*(x2-3.0f*y2);
    sh[24]=0.6258357354491761f*(x2*x2-6.0f*x2*y2+y2*y2);
    #pragma unroll
    for(int lm=0;lm<25;++lm) uv[lm] = rw[DEGA[lm]] * sh[lm];
  }

  float t[25], yn[25];

  // ---- layer 0 CG (uv interleaved: u = .x, v = .y) ----
  #pragma unroll
  for(int i=0;i<25;++i) t[i]=0.0f;
  cg_all<2,2>(wpa, lane, (const float*)uv, ((const float*)uv)+1, t);

  // ---- stage t0, fused (Woa@W1b, Woa@W2b) dense via LDS broadcasts ----
  #pragma unroll
  for(int lm=0;lm<25;++lm) Bt[lm*64+lane] = t[lm];
  #pragma unroll
  for(int lm=0;lm<25;++lm) uv[lm]=(v2f){0.0f,0.0f};
  dense_uv2_deg<0>(WAB, lane, Bt, uv);
  dense_uv2_deg<1>(WAB, lane, Bt, uv);
  dense_uv2_deg<2>(WAB, lane, Bt, uv);
  dense_uv2_deg<3>(WAB, lane, Bt, uv);
  dense_uv2_deg<4>(WAB, lane, Bt, uv);

  // ---- layer 1 CG + twt-folded Wout (LDS broadcasts) ----
  #pragma unroll
  for(int i=0;i<25;++i) t[i]=0.0f;
  cg_all<2,2>(wpb, lane, (const float*)uv, ((const float*)uv)+1, t);
  #pragma unroll
  for(int lm=0;lm<25;++lm) Bt[lm*64+lane] = t[lm];
  #pragma unroll
  for(int lm=0;lm<25;++lm) yn[lm]=0.0f;
  dense_out1_deg<0>(WO, lane, Bt, yn);
  dense_out1_deg<1>(WO, lane, Bt, yn);
  dense_out1_deg<2>(WO, lane, Bt, yn);
  dense_out1_deg<3>(WO, lane, Bt, yn);
  dense_out1_deg<4>(WO, lane, Bt, yn);

  // ---- scale + segment-sum ----
  if(active){
    const int Zi = an[ai];
    const float a = Atab[Zi*64+lane];
    float* o = out + (size_t)ai*1600 + lane;
    #pragma unroll
    for(int lm=0;lm<25;++lm){
      atomicAdd(o + lm*64, yn[lm]*a);
    }
  }
}

// Fallback (R10 readlane structure, un-fused weights) — used only if ws too small.
__global__ __launch_bounds__(256)
void edge_kernel_fb(
    const int* __restrict__ an, const int* __restrict__ nbr, const float* __restrict__ disp,
    const float* __restrict__ Wrad,
    const float* __restrict__ W1a, const float* __restrict__ W2a,
    const float* __restrict__ wpa, const float* __restrict__ Woa,
    const float* __restrict__ W1b, const float* __restrict__ W2b,
    const float* __restrict__ wpb, const float* __restrict__ Wob,
    const float* __restrict__ twt, const float* __restrict__ Atab,
    float* __restrict__ out, int NE)
{
  const int lane = threadIdx.x & 63;
  const int w    = threadIdx.x >> 6;
  const int e0   = blockIdx.x*4 + w;
  const bool active = e0 < NE;
  const int e = active ? e0 : 0;

  const int ai = nbr[2*e];
  const int aj = nbr[2*e+1];
  const float dx = disp[3*e], dy = disp[3*e+1], dz = disp[3*e+2];
  const float r  = sqrtf(fmaf(dx,dx,fmaf(dy,dy,dz*dz)) + 1e-12f);
  const float ir = 1.0f/r;
  const float x = dx*ir, y = dy*ir, z = dz*ir;
  const float fc = (r < 5.0f) ? (0.5f*(cosf(0.62831853071795864769f*r)+1.0f)) : 0.0f;

  const int Zj = an[aj];
  const float* Wr = Wrad + Zj*1024 + lane;
  float rad = 0.0f;
  #pragma unroll
  for(int k=0;k<16;++k){
    const float d  = r - (float)k*(1.0f/3.0f);
    const float rb = __expf(-10.24f*d*d)*fc;
    rad = fmaf(rb, Wr[k*64], rad);
  }

  float rw1[5], rw2[5];
  #pragma unroll
  for(int d=0;d<5;++d){ rw1[d]=0.0f; rw2[d]=0.0f; }
  {
    const float* w1b = W1a + lane;
    const float* w2b = W2a + lane;
    #pragma unroll 2
    for(int f=0; f<64; ++f){
      const float rf = rdl(rad, f);
      #pragma unroll
      for(int d=0;d<5;++d){
        rw1[d] = fmaf(rf, w1b[d*4096 + f*64], rw1[d]);
        rw2[d] = fmaf(rf, w2b[d*4096 + f*64], rw2[d]);
      }
    }
  }

  float u[25], v[25];
  {
    const float x2=x*x, y2=y*y, z2=z*z;
    float sh[25];
    sh[0]=0.28209479177387814f;
    sh[1]=0.4886025119029199f*y;
    sh[2]=0.4886025119029199f*z;
    sh[3]=0.4886025119029199f*x;
    sh[4]=1.0925484305920792f*x*y;
    sh[5]=1.0925484305920792f*y*z;
    sh[6]=0.31539156525252005f*(3.0f*z2-1.0f);
    sh[7]=1.0925484305920792f*x*z;
    sh[8]=0.5462742152960396f*(x2-y2);
    sh[9]=0.5900435899266435f*y*(3.0f*x2-y2);
    sh[10]=2.890611442640554f*x*y*z;
    sh[11]=0.4570457994644658f*y*(5.0f*z2-1.0f);
    sh[12]=0.3731763325901154f*z*(5.0f*z2-3.0f);
    sh[13]=0.4570457994644658f*x*(5.0f*z2-1.0f);
    sh[14]=1.445305721320277f*z*(x2-y2);
    sh[15]=0.5900435899266435f*x*(x2-3.0f*y2);
    sh[16]=2.5033429417967046f*x*y*(x2-y2);
    sh[17]=1.7701307697799304f*y*z*(3.0f*x2-y2);
    sh[18]=0.9461746957575601f*x*y*(7.0f*z2-1.0f);
    sh[19]=0.6690465435572892f*y*z*(7.0f*z2-3.0f);
    sh[20]=0.10578554691520431f*(35.0f*z2*z2-30.0f*z2+3.0f);
    sh[21]=0.6690465435572892f*x*z*(7.0f*z2-3.0f);
    sh[22]=0.47308734787878004f*(x2-y2)*(7.0f*z2-1.0f);
    sh[23]=1.7701307697799304f*x*z*(x2-3.0f*y2);
    sh[24]=0.6258357354491761f*(x2*x2-6.0f*x2*y2+y2*y2);
    #pragma unroll
    for(int lm=0;lm<25;++lm){
      u[lm] = sh[lm]*rw1[DEGA[lm]];
      v[lm] = sh[lm]*rw2[DEGA[lm]];
    }
  }

  float t[25], yn[25];
  #pragma unroll
  for(int i=0;i<25;++i) t[i]=0.0f;
  cg_all<1,1>(wpa, lane, u, v, t);
  {
    #pragma unroll
    for(int lm=0;lm<25;++lm) yn[lm]=0.0f;
    const float* wb = Woa + lane;
    #pragma unroll 2
    for(int f=0; f<64; ++f){
      float wv[5];
      #pragma unroll
      for(int d=0;d<5;++d) wv[d] = wb[d*4096 + f*64];
      #pragma unroll
      for(int lm=0;lm<25;++lm) yn[lm] = fmaf(rdl(t[lm], f), wv[DEGA[lm]], yn[lm]);
    }
  }
  {
    #pragma unroll
    for(int lm=0;lm<25;++lm){ u[lm]=0.0f; v[lm]=0.0f; }
    const float* w1b = W1b + lane;
    const float* w2b = W2b + lane;
    #pragma unroll 2
    for(int f=0; f<64; ++f){
      float w1[5], w2[5];
      #pragma unroll
      for(int d=0;d<5;++d){ w1[d] = w1b[d*4096 + f*64]; w2[d] = w2b[d*4096 + f*64]; }
      #pragma unroll
      for(int lm=0;lm<25;++lm){
        const float yf = rdl(yn[lm], f);
        u[lm] = fmaf(yf, w1[DEGA[lm]], u[lm]);
        v[lm] = fmaf(yf, w2[DEGA[lm]], v[lm]);
      }
    }
  }
  #pragma unroll
  for(int i=0;i<25;++i) t[i]=0.0f;
  cg_all<1,1>(wpb, lane, u, v, t);
  {
    #pragma unroll
    for(int lm=0;lm<25;++lm) yn[lm]=0.0f;
    const float* wb = Wob + lane;
    #pragma unroll 2
    for(int f=0; f<64; ++f){
      float wv[5];
      #pragma unroll
      for(int d=0;d<5;++d) wv[d] = wb[d*4096 + f*64];
      #pragma unroll
      for(int lm=0;lm<25;++lm) yn[lm] = fmaf(rdl(t[lm], f), wv[DEGA[lm]], yn[lm]);
    }
  }

  if(active){
    const int Zi = an[ai];
    const float a = Atab[Zi*64+lane];
    float s[5];
    #pragma unroll
    for(int d=0;d<5;++d) s[d] = a*twt[d*64+lane];
    float* o = out + (size_t)ai*1600 + lane;
    #pragma unroll
    for(int lm=0;lm<25;++lm){
      atomicAdd(o + lm*64, yn[lm]*s[DEGA[lm]]);
    }
  }
}

// ---------------------------------------------------------------------------
extern "C" void kernel_launch(void* const* d_in, const int* in_sizes, int n_in,
                              void* d_out, int out_size, void* d_ws, size_t ws_size,
                              hipStream_t stream)
{
  const int*   an   = (const int*)  d_in[0];
  const int*   nbr  = (const int*)  d_in[1];
  const float* disp = (const float*)d_in[2];
  const float* emb  = (const float*)d_in[3];
  const float* Wemb = (const float*)d_in[4];
  const float* Wrad = (const float*)d_in[5];
  const float* W1a  = (const float*)d_in[6];
  const float* W2a  = (const float*)d_in[7];
  const float* wpa  = (const float*)d_in[8];
  const float* Woa  = (const float*)d_in[9];
  const float* W1b  = (const float*)d_in[10];
  const float* W2b  = (const float*)d_in[11];
  const float* wpb  = (const float*)d_in[12];
  const float* Wob  = (const float*)d_in[13];
  const float* twt  = (const float*)d_in[14];

  const int NA = in_sizes[0];
  const int NE = in_sizes[1]/2;
  const int NS = in_sizes[3]/64;

  float* out = (float*)d_out;
  hipMemsetAsync(out, 0, (size_t)out_size*sizeof(float), stream);

  // ws layout: W12[40960] | WAB[40960] | WO[20480] | Atab[NS*64]
  // (dense prefetch over-reads <=2KB past each slice: stays inside this block)
  const size_t need = (size_t)(40960 + 40960 + 20480 + NS*64) * sizeof(float);
  if(ws_size >= need){
    float* W12  = (float*)d_ws;
    float* WAB  = W12 + 40960;
    float* WO   = WAB + 40960;
    float* Atab = WO  + 20480;
    wfuse_kernel<<<80, 256, 0, stream>>>(W1a,W2a,Woa,W1b,W2b,Wob,twt,W12,WAB,WO);
    atab_kernel<<<NS, 64, 0, stream>>>(emb, Wemb, Atab);
    edge_kernel<<<(NE+1)/2, 128, 0, stream>>>(an, nbr, disp, Wrad,
                                              W12, WAB, wpa, wpb, WO,
                                              Atab, out, NE);
    self_kernel<<<(NA*64+255)/256, 256, 0, stream>>>(an, Atab, out, NA);
  } else {
    float* Atab = (float*)d_ws;
    atab_kernel<<<NS, 64, 0, stream>>>(emb, Wemb, Atab);
    edge_kernel_fb<<<(NE+3)/4, 256, 0, stream>>>(an, nbr, disp, Wrad,
                                                 W1a, W2a, wpa, Woa,
                                                 W1b, W2b, wpb, Wob,
                                                 twt, Atab, out, NE);
    self_kernel<<<(NA*64+255)/256, 256, 0, stream>>>(an, Atab, out, NA);
  }
}

// Round 18
// 965.846 us; speedup vs baseline: 2.1347x; 1.0498x over previous
//
#include <hip/hip_runtime.h>
#include <array>

#define DEV __device__ __forceinline__

typedef float v2f __attribute__((ext_vector_type(2)));

// ---------------------------------------------------------------------------
// Compile-time real Clebsch-Gordan tables (mirror of reference _build_paths)
// ---------------------------------------------------------------------------
namespace cgt {

constexpr double FACT[14] = {1.,1.,2.,6.,24.,120.,720.,5040.,40320.,362880.,
                             3628800.,39916800.,479001600.,6227020800.};

constexpr double csqrt(double x){
  if(x <= 0.0) return 0.0;
  double g = x > 1.0 ? x : 1.0;
  for(int i=0;i<28;++i) g = 0.5*(g + x/g);
  return g;
}

constexpr double cgc(int l1,int m1,int l2,int m2,int l3,int m3){
  if(m3 != m1+m2) return 0.0;
  double pre = (2.0*l3+1.0)*FACT[l1+l2-l3]*FACT[l1-l2+l3]*FACT[-l1+l2+l3]/FACT[l1+l2+l3+1];
  pre = csqrt(pre * FACT[l1+m1]*FACT[l1-m1]*FACT[l2+m2]*FACT[l2-m2]*FACT[l3+m3]*FACT[l3-m3]);
  double s = 0.0;
  for(int k=0;k<=l1+l2-l3;++k){
    int d1=l1+l2-l3-k, d2=l1-m1-k, d3=l2+m2-k, d4=l3-l2+m1+k, d5=l3-l1-m2+k;
    if(d1<0||d2<0||d3<0||d4<0||d5<0) continue;
    double den = FACT[k]*FACT[d1]*FACT[d2]*FACT[d3]*FACT[d4]*FACT[d5];
    s += ((k&1)? -1.0 : 1.0)/den;
  }
  return pre*s;
}

struct C2 { double re, im; };

// U_l[a, m+l] of the complex->real SH change of basis
constexpr C2 uent(int l, int a, int m){
  const double s = 0.70710678118654752440;
  int mr = a - l;
  if(mr == 0) return (m==0) ? C2{1.0,0.0} : C2{0.0,0.0};
  if(mr > 0){
    if(m ==  mr) return C2{ (mr&1)? -s : s, 0.0};
    if(m == -mr) return C2{ s, 0.0};
    return C2{0.0,0.0};
  }
  if(m ==  mr) return C2{0.0, s};
  if(m == -mr) return C2{0.0, ((-mr)&1)? s : -s};
  return C2{0.0,0.0};
}

constexpr float crent(int l1,int l2,int l3,int a,int b,int c){
  double re = 0.0;
  int mrc = c - l3;
  for(int i=0;i<2;++i){
    if(i==1 && a==l1) break;
    int m1 = (i==0) ? (a-l1) : (l1-a);
    for(int j=0;j<2;++j){
      if(j==1 && b==l2) break;
      int m2 = (j==0) ? (b-l2) : (l2-b);
      int m3 = m1+m2;
      if(m3 < -l3 || m3 > l3) continue;
      if(m3 != mrc && m3 != -mrc) continue;   // U3 row-c sparsity
      C2 u1 = uent(l1,a,m1), u2 = uent(l2,b,m2), u3 = uent(l3,c,m3);
      double u3re = u3.re, u3im = -u3.im;     // conj
      double pr = u1.re*u2.re - u1.im*u2.im;
      double pi = u1.re*u2.im + u1.im*u2.re;
      double rr = pr*u3re - pi*u3im;          // Re(u1*u2*conj(u3))
      if(rr == 0.0) continue;
      re += rr * cgc(l1,m1,l2,m2,l3,m3);
    }
  }
  return (float)re;
}

template<int L1,int L2,int L3>
constexpr std::array<float,(2*L1+1)*(2*L2+1)*(2*L3+1)> build_path(){
  std::array<float,(2*L1+1)*(2*L2+1)*(2*L3+1)> r{};
  for(int a=0;a<2*L1+1;++a)
    for(int b=0;b<2*L2+1;++b)
      for(int c=0;c<2*L3+1;++c)
        r[(a*(2*L2+1)+b)*(2*L3+1)+c] = crent(L1,L2,L3,a,b,c);
  return r;
}

} // namespace cgt

// ---------------------------------------------------------------------------
// R18 = R17 + cg wp-prescale.  R17 proved occupancy is scheduler-pinned at
// ~3.5 waves/SIMD regardless of LDS (44.5% with 26.6KB, 13.3KB, and R8's 0KB)
// -> TLP/ILP/prefetch all exhausted.  VALU issue = 49k cyc/edge (68% busy);
// cg dominates (~18k: 1302 (a,b) pairs x [uvw = u*v*wpv -> 2 muls + ~1.5 fma]).
// Pre-scaling the SMALLER side per path (us[a] = u[a]*wpv, <=9 transient regs)
// makes each pair 1 mul: saves ~1130 muls x 2 layers ~ 4.5k cyc/edge (~7-9%).
// ---------------------------------------------------------------------------
__device__ constexpr int DEGA[25] = {0,1,1,1,2,2,2,2,2,3,3,3,3,3,3,3,4,4,4,4,4,4,4,4,4};

DEV v2f fma2(v2f a, v2f b, v2f c){
#if __has_builtin(__builtin_elementwise_fma)
  return __builtin_elementwise_fma(a,b,c);
#else
  return (v2f){fmaf(a.x,b.x,c.x), fmaf(a.y,b.y,c.y)};
#endif
}

DEV float rdl(float v, int l){   // fallback kernel only
  return __int_as_float(__builtin_amdgcn_readlane(__float_as_int(v), l));
}

// One CG path; u,v accessed with compile-time strides (US/VS).
// wp is folded into the side with fewer components (one mul per component),
// so each (a,b) pair costs a single v_mul + per-c fma.
template<int L1,int L2,int L3,int P,int US,int VS>
DEV void cg_path(const float* __restrict__ wp, int lane,
                 const float* __restrict__ u, const float* __restrict__ v,
                 float* __restrict__ t){
  constexpr auto C = cgt::build_path<L1,L2,L3>();
  const float wpv = wp[P*64 + lane];
  if constexpr (L1 <= L2){
    float us[2*L1+1];
    #pragma unroll
    for(int a=0;a<2*L1+1;++a) us[a] = u[(L1*L1+a)*US]*wpv;
    #pragma unroll
    for(int a=0;a<2*L1+1;++a){
      #pragma unroll
      for(int b=0;b<2*L2+1;++b){
        float uvw = 0.0f; bool made = false;
        #pragma unroll
        for(int c=0;c<2*L3+1;++c){
          const float cv = C[(a*(2*L2+1)+b)*(2*L3+1)+c];
          if(cv != 0.0f){
            if(!made){ uvw = us[a]*v[(L2*L2+b)*VS]; made = true; }
            t[L3*L3+c] = fmaf(cv, uvw, t[L3*L3+c]);
          }
        }
      }
    }
  } else {
    float vs[2*L2+1];
    #pragma unroll
    for(int b=0;b<2*L2+1;++b) vs[b] = v[(L2*L2+b)*VS]*wpv;
    #pragma unroll
    for(int a=0;a<2*L1+1;++a){
      #pragma unroll
      for(int b=0;b<2*L2+1;++b){
        float uvw = 0.0f; bool made = false;
        #pragma unroll
        for(int c=0;c<2*L3+1;++c){
          const float cv = C[(a*(2*L2+1)+b)*(2*L3+1)+c];
          if(cv != 0.0f){
            if(!made){ uvw = u[(L1*L1+a)*US]*vs[b]; made = true; }
            t[L3*L3+c] = fmaf(cv, uvw, t[L3*L3+c]);
          }
        }
      }
    }
  }
}

template<int US,int VS>
DEV void cg_all(const float* __restrict__ wp, int lane,
                const float* __restrict__ u, const float* __restrict__ v,
                float* __restrict__ t){
  cg_path<0,0,0,0,US,VS>(wp,lane,u,v,t);  cg_path<0,1,1,1,US,VS>(wp,lane,u,v,t);
  cg_path<0,2,2,2,US,VS>(wp,lane,u,v,t);  cg_path<0,3,3,3,US,VS>(wp,lane,u,v,t);
  cg_path<0,4,4,4,US,VS>(wp,lane,u,v,t);
  cg_path<1,0,1,5,US,VS>(wp,lane,u,v,t);  cg_path<1,1,0,6,US,VS>(wp,lane,u,v,t);
  cg_path<1,1,2,7,US,VS>(wp,lane,u,v,t);  cg_path<1,2,1,8,US,VS>(wp,lane,u,v,t);
  cg_path<1,2,3,9,US,VS>(wp,lane,u,v,t);  cg_path<1,3,2,10,US,VS>(wp,lane,u,v,t);
  cg_path<1,3,4,11,US,VS>(wp,lane,u,v,t); cg_path<1,4,3,12,US,VS>(wp,lane,u,v,t);
  cg_path<2,0,2,13,US,VS>(wp,lane,u,v,t); cg_path<2,1,1,14,US,VS>(wp,lane,u,v,t);
  cg_path<2,1,3,15,US,VS>(wp,lane,u,v,t); cg_path<2,2,0,16,US,VS>(wp,lane,u,v,t);
  cg_path<2,2,2,17,US,VS>(wp,lane,u,v,t); cg_path<2,2,4,18,US,VS>(wp,lane,u,v,t);
  cg_path<2,3,1,19,US,VS>(wp,lane,u,v,t); cg_path<2,3,3,20,US,VS>(wp,lane,u,v,t);
  cg_path<2,4,2,21,US,VS>(wp,lane,u,v,t); cg_path<2,4,4,22,US,VS>(wp,lane,u,v,t);
  cg_path<3,0,3,23,US,VS>(wp,lane,u,v,t); cg_path<3,1,2,24,US,VS>(wp,lane,u,v,t);
  cg_path<3,1,4,25,US,VS>(wp,lane,u,v,t); cg_path<3,2,1,26,US,VS>(wp,lane,u,v,t);
  cg_path<3,2,3,27,US,VS>(wp,lane,u,v,t); cg_path<3,3,0,28,US,VS>(wp,lane,u,v,t);
  cg_path<3,3,2,29,US,VS>(wp,lane,u,v,t); cg_path<3,3,4,30,US,VS>(wp,lane,u,v,t);
  cg_path<3,4,1,31,US,VS>(wp,lane,u,v,t); cg_path<3,4,3,32,US,VS>(wp,lane,u,v,t);
  cg_path<4,0,4,33,US,VS>(wp,lane,u,v,t); cg_path<4,1,3,34,US,VS>(wp,lane,u,v,t);
  cg_path<4,2,2,35,US,VS>(wp,lane,u,v,t); cg_path<4,2,4,36,US,VS>(wp,lane,u,v,t);
  cg_path<4,3,1,37,US,VS>(wp,lane,u,v,t); cg_path<4,3,3,38,US,VS>(wp,lane,u,v,t);
  cg_path<4,4,0,39,US,VS>(wp,lane,u,v,t); cg_path<4,4,2,40,US,VS>(wp,lane,u,v,t);
  cg_path<4,4,4,41,US,VS>(wp,lane,u,v,t);
}

// Degree-D packed dense with 1-deep weight prefetch:
// uv[lm] += sum_f Bt[lm][f]*(WA,WB)[D][f][g].  Bt = full [25][64] staging.
template<int D>
DEV void dense_uv2_deg(const float* __restrict__ Wint, int lane,
                       const float* __restrict__ Bt, v2f* __restrict__ uv){
  constexpr int L0 = D*D, N = 2*D+1;
  const float* p = Wint + lane*2 + D*8192;      // (D*4096)*2
  v2f w0 = *(const v2f*)(p);
  v2f w1 = *(const v2f*)(p+128);
  v2f w2 = *(const v2f*)(p+256);
  v2f w3 = *(const v2f*)(p+384);
  #pragma unroll 1
  for(int f0=0; f0<64; f0+=4){
    const float* pn = p + 512;                  // next f-chunk (over-reads 2KB
    v2f n0 = *(const v2f*)(pn);                 //  past slice end on last iter:
    v2f n1 = *(const v2f*)(pn+128);             //  lands in adjacent ws region)
    v2f n2 = *(const v2f*)(pn+256);
    v2f n3 = *(const v2f*)(pn+384);
    #pragma unroll
    for(int m=0;m<N;++m){
      const float4 tv = *(const float4*)(Bt + (L0+m)*64 + f0);
      v2f acc = uv[L0+m];
      acc = fma2(w0,(v2f){tv.x,tv.x},acc);
      acc = fma2(w1,(v2f){tv.y,tv.y},acc);
      acc = fma2(w2,(v2f){tv.z,tv.z},acc);
      acc = fma2(w3,(v2f){tv.w,tv.w},acc);
      uv[L0+m] = acc;
    }
    w0=n0; w1=n1; w2=n2; w3=n3; p = pn;
  }
}

// Degree-D scalar out dense with 1-deep weight prefetch.
template<int D>
DEV void dense_out1_deg(const float* __restrict__ W, int lane,
                        const float* __restrict__ Bt, float* __restrict__ yn){
  constexpr int L0 = D*D, N = 2*D+1;
  const float* p = W + lane + D*4096;
  float w0 = p[0], w1 = p[64], w2 = p[128], w3 = p[192];
  #pragma unroll 1
  for(int f0=0; f0<64; f0+=4){
    const float* pn = p + 256;
    float n0 = pn[0], n1 = pn[64], n2 = pn[128], n3 = pn[192];
    #pragma unroll
    for(int m=0;m<N;++m){
      const float4 tv = *(const float4*)(Bt + (L0+m)*64 + f0);
      float acc = yn[L0+m];
      acc = fmaf(tv.x,w0,acc);
      acc = fmaf(tv.y,w1,acc);
      acc = fmaf(tv.z,w2,acc);
      acc = fmaf(tv.w,w3,acc);
      yn[L0+m] = acc;
    }
    w0=n0; w1=n1; w2=n2; w3=n3; p = pn;
  }
}

// ---------------------------------------------------------------------------
// Kernels
// ---------------------------------------------------------------------------
// Precompute: W12 = interleave(W1a,W2a); WAB = interleave(Woa@W1b, Woa@W2b);
// WO = Wob * twt.  One thread per (d,f,g).
__global__ void wfuse_kernel(const float* __restrict__ W1a, const float* __restrict__ W2a,
                             const float* __restrict__ Woa, const float* __restrict__ W1b,
                             const float* __restrict__ W2b, const float* __restrict__ Wob,
                             const float* __restrict__ twt,
                             float* __restrict__ W12, float* __restrict__ WAB,
                             float* __restrict__ WO){
  const int i = blockIdx.x*256 + threadIdx.x;   // 0 .. 20479
  if(i >= 20480) return;
  const int d = i >> 12, rem = i & 4095, f = rem >> 6, g = rem & 63;
  W12[2*i+0] = W1a[i];
  W12[2*i+1] = W2a[i];
  const float* wo  = Woa + d*4096 + f*64;   // row f: [h]
  const float* wb1 = W1b + d*4096 + g;      // col g: [h][g] stride 64
  const float* wb2 = W2b + d*4096 + g;
  float sa = 0.0f, sb = 0.0f;
  for(int h=0; h<64; ++h){
    const float a = wo[h];
    sa = fmaf(a, wb1[h*64], sa);
    sb = fmaf(a, wb2[h*64], sb);
  }
  WAB[2*i+0] = sa;
  WAB[2*i+1] = sb;
  WO[i] = Wob[i] * twt[d*64 + g];
}

// A[s][g] = emb_table[s] @ W_emb_t  (species-deduped edge scale table)
__global__ void atab_kernel(const float* __restrict__ emb, const float* __restrict__ Wemb,
                            float* __restrict__ A){
  const int s = blockIdx.x;
  const int g = threadIdx.x;
  float acc = 0.0f;
  for(int f=0; f<64; ++f) acc = fmaf(emb[s*64+f], Wemb[f*64+g], acc);
  A[s*64+g] = acc;
}

// out[a,0,:] += A[Z[a]]
__global__ void self_kernel(const int* __restrict__ an, const float* __restrict__ A,
                            float* __restrict__ out, int NA){
  const int i = blockIdx.x*256 + threadIdx.x;
  if(i < NA*64){
    const int a = i>>6, g = i&63;
    out[(size_t)a*1600 + g] += A[an[a]*64 + g];
  }
}

// Fused edge kernel: one wave per edge (lane = feature g).
// 2 waves per block: LDS 2x1664 floats = 13312B/block.
__global__ __launch_bounds__(128)
void edge_kernel(
    const int* __restrict__ an, const int* __restrict__ nbr, const float* __restrict__ disp,
    const float* __restrict__ Wrad,
    const float* __restrict__ W12, const float* __restrict__ WAB,
    const float* __restrict__ wpa, const float* __restrict__ wpb,
    const float* __restrict__ WO, const float* __restrict__ Atab,
    float* __restrict__ out, int NE)
{
  __shared__ __align__(16) float lds[2*1664];
  const int lane = threadIdx.x & 63;
  const int w    = threadIdx.x >> 6;
  const int e0   = blockIdx.x*2 + w;
  const bool active = e0 < NE;
  const int e = active ? e0 : 0;
  float* Bt   = lds + w*1664;    // [25][64] t staging (wave-private)
  float* Brad = Bt + 1600;       // [64] rad staging

  // ---- radial scalar chain (wave-uniform r) + per-lane rad[f=lane] ----
  const int ai = nbr[2*e];
  const int aj = nbr[2*e+1];
  const float dx = disp[3*e], dy = disp[3*e+1], dz = disp[3*e+2];
  const float r  = sqrtf(fmaf(dx,dx,fmaf(dy,dy,dz*dz)) + 1e-12f);
  const float ir = 1.0f/r;
  const float x = dx*ir, y = dy*ir, z = dz*ir;
  const float fc = (r < 5.0f) ? (0.5f*(cosf(0.62831853071795864769f*r)+1.0f)) : 0.0f;

  const int Zj = an[aj];
  const float* Wr = Wrad + Zj*1024 + lane;
  float rad = 0.0f;
  #pragma unroll
  for(int k=0;k<16;++k){
    const float d  = r - (float)k*(1.0f/3.0f);
    const float rb = __expf(-10.24f*d*d)*fc;
    rad = fmaf(rb, Wr[k*64], rad);
  }
  Brad[lane] = rad;   // same-wave LDS ops are in-order: no barrier needed

  // ---- layer-0 rank-1 collapse with packed (W1a,W2a):
  //      rw[d] = sum_f rad[f] * (W1a,W2a)[d][f][g], rad[f] via LDS broadcast
  v2f rw[5];
  #pragma unroll
  for(int d=0;d<5;++d) rw[d]=(v2f){0.0f,0.0f};
  {
    const float* wb = W12 + lane*2;
    #pragma unroll 1
    for(int f0=0; f0<64; f0+=4){
      const float4 rv = *(const float4*)(Brad + f0);
      #pragma unroll
      for(int d=0;d<5;++d){
        const float* p = wb + (d*4096 + f0*64)*2;
        const v2f w0 = *(const v2f*)(p);
        const v2f w1 = *(const v2f*)(p+128);
        const v2f w2 = *(const v2f*)(p+256);
        const v2f w3 = *(const v2f*)(p+384);
        v2f acc = rw[d];
        acc = fma2(w0,(v2f){rv.x,rv.x},acc);
        acc = fma2(w1,(v2f){rv.y,rv.y},acc);
        acc = fma2(w2,(v2f){rv.z,rv.z},acc);
        acc = fma2(w3,(v2f){rv.w,rv.w},acc);
        rw[d] = acc;
      }
    }
  }

  v2f uv[25];
  {
    // spherical harmonics (wave-uniform scalars), consumed immediately
    const float x2=x*x, y2=y*y, z2=z*z;
    float sh[25];
    sh[0]=0.28209479177387814f;
    sh[1]=0.4886025119029199f*y;
    sh[2]=0.4886025119029199f*z;
    sh[3]=0.4886025119029199f*x;
    sh[4]=1.0925484305920792f*x*y;
    sh[5]=1.0925484305920792f*y*z;
    sh[6]=0.31539156525252005f*(3.0f*z2-1.0f);
    sh[7]=1.0925484305920792f*x*z;
    sh[8]=0.5462742152960396f*(x2-y2);
    sh[9]=0.5900435899266435f*y*(3.0f*x2-y2);
    sh[10]=2.890611442640554f*x*y*z;
    sh[11]=0.4570457994644658f*y*(5.0f*z2-1.0f);
    sh[12]=0.3731763325901154f*z*(5.0f*z2-3.0f);
    sh[13]=0.4570457994644658f*x*(5.0f*z2-1.0f);
    sh[14]=1.445305721320277f*z*(x2-y2);
    sh[15]=0.5900435899266435f*x*(x2-3.0f*y2);
    sh[16]=2.5033429417967046f*x*y*(x2-y2);
    sh[17]=1.7701307697799304f*y*z*(3.0f*x2-y2);
    sh[18]=0.9461746957575601f*x*y*(7.0f*z2-1.0f);
    sh[19]=0.6690465435572892f*y*z*(7.0f*z2-3.0f);
    sh[20]=0.10578554691520431f*(35.0f*z2*z2-30.0f*z2+3.0f);
    sh[21]=0.6690465435572892f*x*z*(7.0f*z2-3.0f);
    sh[22]=0.47308734787878004f*(x2-y2)*(7.0f*z2-1.0f);
    sh[23]=1.7701307697799304f*x*z*(x2-3.0f*y2);
    sh[24]=0.6258357354491761f*(x2*x2-6.0f*x2*y2+y2*y2);
    #pragma unroll
    for(int lm=0;lm<25;++lm) uv[lm] = rw[DEGA[lm]] * sh[lm];
  }

  float t[25], yn[25];

  // ---- layer 0 CG (uv interleaved: u = .x, v = .y) ----
  #pragma unroll
  for(int i=0;i<25;++i) t[i]=0.0f;
  cg_all<2,2>(wpa, lane, (const float*)uv, ((const float*)uv)+1, t);

  // ---- stage t0, fused (Woa@W1b, Woa@W2b) dense via LDS broadcasts ----
  #pragma unroll
  for(int lm=0;lm<25;++lm) Bt[lm*64+lane] = t[lm];
  #pragma unroll
  for(int lm=0;lm<25;++lm) uv[lm]=(v2f){0.0f,0.0f};
  dense_uv2_deg<0>(WAB, lane, Bt, uv);
  dense_uv2_deg<1>(WAB, lane, Bt, uv);
  dense_uv2_deg<2>(WAB, lane, Bt, uv);
  dense_uv2_deg<3>(WAB, lane, Bt, uv);
  dense_uv2_deg<4>(WAB, lane, Bt, uv);

  // ---- layer 1 CG + twt-folded Wout (LDS broadcasts) ----
  #pragma unroll
  for(int i=0;i<25;++i) t[i]=0.0f;
  cg_all<2,2>(wpb, lane, (const float*)uv, ((const float*)uv)+1, t);
  #pragma unroll
  for(int lm=0;lm<25;++lm) Bt[lm*64+lane] = t[lm];
  #pragma unroll
  for(int lm=0;lm<25;++lm) yn[lm]=0.0f;
  dense_out1_deg<0>(WO, lane, Bt, yn);
  dense_out1_deg<1>(WO, lane, Bt, yn);
  dense_out1_deg<2>(WO, lane, Bt, yn);
  dense_out1_deg<3>(WO, lane, Bt, yn);
  dense_out1_deg<4>(WO, lane, Bt, yn);

  // ---- scale + segment-sum ----
  if(active){
    const int Zi = an[ai];
    const float a = Atab[Zi*64+lane];
    float* o = out + (size_t)ai*1600 + lane;
    #pragma unroll
    for(int lm=0;lm<25;++lm){
      atomicAdd(o + lm*64, yn[lm]*a);
    }
  }
}

// Fallback (R10 readlane structure, un-fused weights) — used only if ws too small.
__global__ __launch_bounds__(256)
void edge_kernel_fb(
    const int* __restrict__ an, const int* __restrict__ nbr, const float* __restrict__ disp,
    const float* __restrict__ Wrad,
    const float* __restrict__ W1a, const float* __restrict__ W2a,
    const float* __restrict__ wpa, const float* __restrict__ Woa,
    const float* __restrict__ W1b, const float* __restrict__ W2b,
    const float* __restrict__ wpb, const float* __restrict__ Wob,
    const float* __restrict__ twt, const float* __restrict__ Atab,
    float* __restrict__ out, int NE)
{
  const int lane = threadIdx.x & 63;
  const int w    = threadIdx.x >> 6;
  const int e0   = blockIdx.x*4 + w;
  const bool active = e0 < NE;
  const int e = active ? e0 : 0;

  const int ai = nbr[2*e];
  const int aj = nbr[2*e+1];
  const float dx = disp[3*e], dy = disp[3*e+1], dz = disp[3*e+2];
  const float r  = sqrtf(fmaf(dx,dx,fmaf(dy,dy,dz*dz)) + 1e-12f);
  const float ir = 1.0f/r;
  const float x = dx*ir, y = dy*ir, z = dz*ir;
  const float fc = (r < 5.0f) ? (0.5f*(cosf(0.62831853071795864769f*r)+1.0f)) : 0.0f;

  const int Zj = an[aj];
  const float* Wr = Wrad + Zj*1024 + lane;
  float rad = 0.0f;
  #pragma unroll
  for(int k=0;k<16;++k){
    const float d  = r - (float)k*(1.0f/3.0f);
    const float rb = __expf(-10.24f*d*d)*fc;
    rad = fmaf(rb, Wr[k*64], rad);
  }

  float rw1[5], rw2[5];
  #pragma unroll
  for(int d=0;d<5;++d){ rw1[d]=0.0f; rw2[d]=0.0f; }
  {
    const float* w1b = W1a + lane;
    const float* w2b = W2a + lane;
    #pragma unroll 2
    for(int f=0; f<64; ++f){
      const float rf = rdl(rad, f);
      #pragma unroll
      for(int d=0;d<5;++d){
        rw1[d] = fmaf(rf, w1b[d*4096 + f*64], rw1[d]);
        rw2[d] = fmaf(rf, w2b[d*4096 + f*64], rw2[d]);
      }
    }
  }

  float u[25], v[25];
  {
    const float x2=x*x, y2=y*y, z2=z*z;
    float sh[25];
    sh[0]=0.28209479177387814f;
    sh[1]=0.4886025119029199f*y;
    sh[2]=0.4886025119029199f*z;
    sh[3]=0.4886025119029199f*x;
    sh[4]=1.0925484305920792f*x*y;
    sh[5]=1.0925484305920792f*y*z;
    sh[6]=0.31539156525252005f*(3.0f*z2-1.0f);
    sh[7]=1.0925484305920792f*x*z;
    sh[8]=0.5462742152960396f*(x2-y2);
    sh[9]=0.5900435899266435f*y*(3.0f*x2-y2);
    sh[10]=2.890611442640554f*x*y*z;
    sh[11]=0.4570457994644658f*y*(5.0f*z2-1.0f);
    sh[12]=0.3731763325901154f*z*(5.0f*z2-3.0f);
    sh[13]=0.4570457994644658f*x*(5.0f*z2-1.0f);
    sh[14]=1.445305721320277f*z*(x2-y2);
    sh[15]=0.5900435899266435f*x*(x2-3.0f*y2);
    sh[16]=2.5033429417967046f*x*y*(x2-y2);
    sh[17]=1.7701307697799304f*y*z*(3.0f*x2-y2);
    sh[18]=0.9461746957575601f*x*y*(7.0f*z2-1.0f);
    sh[19]=0.6690465435572892f*y*z*(7.0f*z2-3.0f);
    sh[20]=0.10578554691520431f*(35.0f*z2*z2-30.0f*z2+3.0f);
    sh[21]=0.6690465435572892f*x*z*(7.0f*z2-3.0f);
    sh[22]=0.47308734787878004f*(x2-y2)*(7.0f*z2-1.0f);
    sh[23]=1.7701307697799304f*x*z*(x2-3.0f*y2);
    sh[24]=0.6258357354491761f*(x2*x2-6.0f*x2*y2+y2*y2);
    #pragma unroll
    for(int lm=0;lm<25;++lm){
      u[lm] = sh[lm]*rw1[DEGA[lm]];
      v[lm] = sh[lm]*rw2[DEGA[lm]];
    }
  }

  float t[25], yn[25];
  #pragma unroll
  for(int i=0;i<25;++i) t[i]=0.0f;
  cg_all<1,1>(wpa, lane, u, v, t);
  {
    #pragma unroll
    for(int lm=0;lm<25;++lm) yn[lm]=0.0f;
    const float* wb = Woa + lane;
    #pragma unroll 2
    for(int f=0; f<64; ++f){
      float wv[5];
      #pragma unroll
      for(int d=0;d<5;++d) wv[d] = wb[d*4096 + f*64];
      #pragma unroll
      for(int lm=0;lm<25;++lm) yn[lm] = fmaf(rdl(t[lm], f), wv[DEGA[lm]], yn[lm]);
    }
  }
  {
    #pragma unroll
    for(int lm=0;lm<25;++lm){ u[lm]=0.0f; v[lm]=0.0f; }
    const float* w1b = W1b + lane;
    const float* w2b = W2b + lane;
    #pragma unroll 2
    for(int f=0; f<64; ++f){
      float w1[5], w2[5];
      #pragma unroll
      for(int d=0;d<5;++d){ w1[d] = w1b[d*4096 + f*64]; w2[d] = w2b[d*4096 + f*64]; }
      #pragma unroll
      for(int lm=0;lm<25;++lm){
        const float yf = rdl(yn[lm], f);
        u[lm] = fmaf(yf, w1[DEGA[lm]], u[lm]);
        v[lm] = fmaf(yf, w2[DEGA[lm]], v[lm]);
      }
    }
  }
  #pragma unroll
  for(int i=0;i<25;++i) t[i]=0.0f;
  cg_all<1,1>(wpb, lane, u, v, t);
  {
    #pragma unroll
    for(int lm=0;lm<25;++lm) yn[lm]=0.0f;
    const float* wb = Wob + lane;
    #pragma unroll 2
    for(int f=0; f<64; ++f){
      float wv[5];
      #pragma unroll
      for(int d=0;d<5;++d) wv[d] = wb[d*4096 + f*64];
      #pragma unroll
      for(int lm=0;lm<25;++lm) yn[lm] = fmaf(rdl(t[lm], f), wv[DEGA[lm]], yn[lm]);
    }
  }

  if(active){
    const int Zi = an[ai];
    const float a = Atab[Zi*64+lane];
    float s[5];
    #pragma unroll
    for(int d=0;d<5;++d) s[d] = a*twt[d*64+lane];
    float* o = out + (size_t)ai*1600 + lane;
    #pragma unroll
    for(int lm=0;lm<25;++lm){
      atomicAdd(o + lm*64, yn[lm]*s[DEGA[lm]]);
    }
  }
}

// ---------------------------------------------------------------------------
extern "C" void kernel_launch(void* const* d_in, const int* in_sizes, int n_in,
                              void* d_out, int out_size, void* d_ws, size_t ws_size,
                              hipStream_t stream)
{
  const int*   an   = (const int*)  d_in[0];
  const int*   nbr  = (const int*)  d_in[1];
  const float* disp = (const float*)d_in[2];
  const float* emb  = (const float*)d_in[3];
  const float* Wemb = (const float*)d_in[4];
  const float* Wrad = (const float*)d_in[5];
  const float* W1a  = (const float*)d_in[6];
  const float* W2a  = (const float*)d_in[7];
  const float* wpa  = (const float*)d_in[8];
  const float* Woa  = (const float*)d_in[9];
  const float* W1b  = (const float*)d_in[10];
  const float* W2b  = (const float*)d_in[11];
  const float* wpb  = (const float*)d_in[12];
  const float* Wob  = (const float*)d_in[13];
  const float* twt  = (const float*)d_in[14];

  const int NA = in_sizes[0];
  const int NE = in_sizes[1]/2;
  const int NS = in_sizes[3]/64;

  float* out = (float*)d_out;
  hipMemsetAsync(out, 0, (size_t)out_size*sizeof(float), stream);

  // ws layout: W12[40960] | WAB[40960] | WO[20480] | Atab[NS*64]
  // (dense prefetch over-reads <=2KB past each slice: stays inside this block)
  const size_t need = (size_t)(40960 + 40960 + 20480 + NS*64) * sizeof(float);
  if(ws_size >= need){
    float* W12  = (float*)d_ws;
    float* WAB  = W12 + 40960;
    float* WO   = WAB + 40960;
    float* Atab = WO  + 20480;
    wfuse_kernel<<<80, 256, 0, stream>>>(W1a,W2a,Woa,W1b,W2b,Wob,twt,W12,WAB,WO);
    atab_kernel<<<NS, 64, 0, stream>>>(emb, Wemb, Atab);
    edge_kernel<<<(NE+1)/2, 128, 0, stream>>>(an, nbr, disp, Wrad,
                                              W12, WAB, wpa, wpb, WO,
                                              Atab, out, NE);
    self_kernel<<<(NA*64+255)/256, 256, 0, stream>>>(an, Atab, out, NA);
  } else {
    float* Atab = (float*)d_ws;
    atab_kernel<<<NS, 64, 0, stream>>>(emb, Wemb, Atab);
    edge_kernel_fb<<<(NE+3)/4, 256, 0, stream>>>(an, nbr, disp, Wrad,
                                                 W1a, W2a, wpa, Woa,
                                                 W1b, W2b, wpb, Wob,
                                                 twt, Atab, out, NE);
    self_kernel<<<(NA*64+255)/256, 256, 0, stream>>>(an, Atab, out, NA);
  }
}